// Round 4
// baseline (809.487 us; speedup 1.0000x reference)
//
#include <hip/hip_runtime.h>
#include <hip/hip_bf16.h>

#define NN 50000
#define EE 800000
#define DD 64
#define NBINS 782                 // ceil(NN / 64)
#define PA_BLOCKS 128
#define PA_CHUNK (EE / PA_BLOCKS) // 6250
#define ASTRIDE 68                // padded LDS row stride (floats)

// ---------------- global per-bin histogram ---------------------------------
__global__ void binhist_kernel(const int* __restrict__ dst, int* __restrict__ binCount) {
    __shared__ int hist[NBINS];
    const int tid = threadIdx.x;
    for (int i = tid; i < NBINS; i += 256) hist[i] = 0;
    __syncthreads();
    const int e0 = blockIdx.x * PA_CHUNK;
    for (int e = e0 + tid; e < e0 + PA_CHUNK; e += 256)
        atomicAdd(&hist[dst[e] >> 6], 1);
    __syncthreads();
    for (int i = tid; i < NBINS; i += 256)
        if (hist[i]) atomicAdd(&binCount[i], hist[i]);
}

// ---------------- exclusive scan over 782 bins (one block) -----------------
__global__ void binscan_kernel(const int* __restrict__ binCount,
                               int* __restrict__ binBase, int* __restrict__ binCursor) {
    __shared__ int s[1024];
    const int tid = threadIdx.x;
    int v = (tid < NBINS) ? binCount[tid] : 0;
    s[tid] = v;
    __syncthreads();
    #pragma unroll
    for (int o = 1; o < 1024; o <<= 1) {
        int t = (tid >= o) ? s[tid - o] : 0;
        __syncthreads();
        s[tid] += t;
        __syncthreads();
    }
    if (tid < NBINS) {
        int b = s[tid] - v;        // exclusive
        binBase[tid] = b;
        binCursor[tid] = b;
    }
    if (tid == 0) binBase[NBINS] = EE;
}

// ---------------- scatter edges into bin segments --------------------------
// Per-(block,bin) contiguous ranges: every 64B line of ebuf is written by one
// block (= one XCD L2) -> full-line writebacks instead of 52MB partials.
__global__ void binscatter_kernel(const int* __restrict__ src, const int* __restrict__ dst,
                                  int* __restrict__ binCursor, unsigned* __restrict__ ebuf) {
    __shared__ int hist[NBINS];
    __shared__ int base[NBINS];
    const int tid = threadIdx.x;
    for (int i = tid; i < NBINS; i += 256) hist[i] = 0;
    __syncthreads();
    const int e0 = blockIdx.x * PA_CHUNK;
    for (int e = e0 + tid; e < e0 + PA_CHUNK; e += 256)
        atomicAdd(&hist[dst[e] >> 6], 1);
    __syncthreads();
    for (int i = tid; i < NBINS; i += 256) {
        int c = hist[i];
        base[i] = c ? atomicAdd(&binCursor[i], c) : 0;
        hist[i] = 0;               // reuse as local cursor
    }
    __syncthreads();
    for (int e = e0 + tid; e < e0 + PA_CHUNK; e += 256) {
        int d = dst[e];
        int b = d >> 6;
        int off = atomicAdd(&hist[b], 1);
        ebuf[base[b] + off] = ((unsigned)(d & 63) << 16) | (unsigned)src[e];
    }
}

// ---------------- per-bin aggregate: mean of neighbor rows into agg --------
// One block per 64-node bin; LDS accumulator; coalesced edge-list reads;
// 16 lanes (float4 each) per edge; 4-edge unroll for latency hiding.
__launch_bounds__(256)
__global__ void binagg_kernel(const float* __restrict__ feat,
                              const unsigned* __restrict__ ebuf,
                              const int* __restrict__ binBase,
                              float* __restrict__ agg) {
    __shared__ float acc[64 * ASTRIDE];
    __shared__ float dcount[64];
    const int tid = threadIdx.x;
    for (int i = tid; i < 64 * ASTRIDE; i += 256) acc[i] = 0.f;
    if (tid < 64) dcount[tid] = 0.f;
    __syncthreads();

    const int b = blockIdx.x;
    const int e0 = binBase[b], e1 = binBase[b + 1];
    const int lane = tid & 15;
    const int q = lane << 2;
    const int eslot = tid >> 4;     // 0..15

    int e = e0 + eslot;
    for (; e + 48 < e1; e += 64) {
        unsigned p0 = ebuf[e];
        unsigned p1 = ebuf[e + 16];
        unsigned p2 = ebuf[e + 32];
        unsigned p3 = ebuf[e + 48];
        float4 v0 = *reinterpret_cast<const float4*>(feat + (size_t)(p0 & 0xFFFFu) * DD + q);
        float4 v1 = *reinterpret_cast<const float4*>(feat + (size_t)(p1 & 0xFFFFu) * DD + q);
        float4 v2 = *reinterpret_cast<const float4*>(feat + (size_t)(p2 & 0xFFFFu) * DD + q);
        float4 v3 = *reinterpret_cast<const float4*>(feat + (size_t)(p3 & 0xFFFFu) * DD + q);
        int a0 = (int)(p0 >> 16) * ASTRIDE + q;
        int a1 = (int)(p1 >> 16) * ASTRIDE + q;
        int a2 = (int)(p2 >> 16) * ASTRIDE + q;
        int a3 = (int)(p3 >> 16) * ASTRIDE + q;
        atomicAdd(&acc[a0 + 0], v0.x); atomicAdd(&acc[a0 + 1], v0.y);
        atomicAdd(&acc[a0 + 2], v0.z); atomicAdd(&acc[a0 + 3], v0.w);
        atomicAdd(&acc[a1 + 0], v1.x); atomicAdd(&acc[a1 + 1], v1.y);
        atomicAdd(&acc[a1 + 2], v1.z); atomicAdd(&acc[a1 + 3], v1.w);
        atomicAdd(&acc[a2 + 0], v2.x); atomicAdd(&acc[a2 + 1], v2.y);
        atomicAdd(&acc[a2 + 2], v2.z); atomicAdd(&acc[a2 + 3], v2.w);
        atomicAdd(&acc[a3 + 0], v3.x); atomicAdd(&acc[a3 + 1], v3.y);
        atomicAdd(&acc[a3 + 2], v3.z); atomicAdd(&acc[a3 + 3], v3.w);
        if (lane == 0) {
            atomicAdd(&dcount[p0 >> 16], 1.f);
            atomicAdd(&dcount[p1 >> 16], 1.f);
            atomicAdd(&dcount[p2 >> 16], 1.f);
            atomicAdd(&dcount[p3 >> 16], 1.f);
        }
    }
    for (; e < e1; e += 16) {
        unsigned p0 = ebuf[e];
        float4 v0 = *reinterpret_cast<const float4*>(feat + (size_t)(p0 & 0xFFFFu) * DD + q);
        int a0 = (int)(p0 >> 16) * ASTRIDE + q;
        atomicAdd(&acc[a0 + 0], v0.x); atomicAdd(&acc[a0 + 1], v0.y);
        atomicAdd(&acc[a0 + 2], v0.z); atomicAdd(&acc[a0 + 3], v0.w);
        if (lane == 0) atomicAdd(&dcount[p0 >> 16], 1.f);
    }
    __syncthreads();

    const int nodeBase = b * 64;
    for (int t = tid; t < 1024; t += 256) {     // 64 nodes x 16 float4-chunks
        int n = t >> 4;
        int qq = (t & 15) << 2;
        int node = nodeBase + n;
        if (node < NN) {
            float dc = dcount[n];
            float iv = (dc > 0.f) ? (1.0f / dc) : 0.0f;
            float4 r;
            r.x = acc[n * ASTRIDE + qq + 0] * iv;
            r.y = acc[n * ASTRIDE + qq + 1] * iv;
            r.z = acc[n * ASTRIDE + qq + 2] * iv;
            r.w = acc[n * ASTRIDE + qq + 3] * iv;
            *reinterpret_cast<float4*>(agg + (size_t)node * DD + qq) = r;
        }
    }
}

// ---------------- fused SAGE layer: out = [agg | xin] @ [Wl;Wr] + b --------
__launch_bounds__(256)
__global__ void layer_kernel(const float* __restrict__ agg,
                             const float* __restrict__ xin,
                             const float* __restrict__ Wl,
                             const float* __restrict__ Wr,
                             const float* __restrict__ bias,
                             float* __restrict__ outp,
                             int relu) {
    __shared__ float A[64 * 128];   // [node][k^sw], sw = (node&7)<<2
    __shared__ float W[128 * 64];   // [k][j]
    const int tid = threadIdx.x;
    const int base = blockIdx.x * 64;

    #pragma unroll
    for (int i = 0; i < 8; ++i) {
        int idx = (i * 256 + tid) * 4;       // 0..8191
        int k = idx >> 6, j = idx & 63;
        const float* sp = (k < 64) ? (Wl + k * 64 + j) : (Wr + (k - 64) * 64 + j);
        *reinterpret_cast<float4*>(&W[idx]) = *reinterpret_cast<const float4*>(sp);
    }

    #pragma unroll
    for (int i = 0; i < 8; ++i) {
        int t2 = i * 256 + tid;              // 0..2047
        int n  = t2 >> 5;                    // node in tile 0..63
        int c4 = (t2 & 31) * 4;              // k chunk 0,4,...,124
        int node = base + n;
        float4 v = make_float4(0.f, 0.f, 0.f, 0.f);
        if (node < NN) {
            if (c4 < 64)
                v = *reinterpret_cast<const float4*>(agg + (size_t)node * DD + c4);
            else
                v = *reinterpret_cast<const float4*>(xin + (size_t)node * DD + (c4 - 64));
        }
        int sw = (n & 7) << 2;
        *reinterpret_cast<float4*>(&A[n * 128 + (c4 ^ sw)]) = v;
    }
    __syncthreads();

    const int tc = (tid & 15) * 4;
    const int tr = (tid >> 4) * 4;

    float acc[4][4];
    float4 bv = *reinterpret_cast<const float4*>(bias + tc);
    #pragma unroll
    for (int i = 0; i < 4; ++i) {
        acc[i][0] = bv.x; acc[i][1] = bv.y; acc[i][2] = bv.z; acc[i][3] = bv.w;
    }

    #pragma unroll 8
    for (int k = 0; k < 128; k += 4) {
        float av[4][4];
        #pragma unroll
        for (int i = 0; i < 4; ++i) {
            int row = tr + i;
            float4 a = *reinterpret_cast<const float4*>(
                &A[row * 128 + (k ^ ((row & 7) << 2))]);
            av[i][0] = a.x; av[i][1] = a.y; av[i][2] = a.z; av[i][3] = a.w;
        }
        #pragma unroll
        for (int kk = 0; kk < 4; ++kk) {
            float4 w = *reinterpret_cast<const float4*>(&W[(k + kk) * 64 + tc]);
            #pragma unroll
            for (int i = 0; i < 4; ++i) {
                acc[i][0] += av[i][kk] * w.x;
                acc[i][1] += av[i][kk] * w.y;
                acc[i][2] += av[i][kk] * w.z;
                acc[i][3] += av[i][kk] * w.w;
            }
        }
    }

    #pragma unroll
    for (int i = 0; i < 4; ++i) {
        int node = base + tr + i;
        if (node < NN) {
            float4 r = make_float4(acc[i][0], acc[i][1], acc[i][2], acc[i][3]);
            if (relu) {
                r.x = fmaxf(r.x, 0.f); r.y = fmaxf(r.y, 0.f);
                r.z = fmaxf(r.z, 0.f); r.w = fmaxf(r.w, 0.f);
            }
            *reinterpret_cast<float4*>(outp + (size_t)node * DD + tc) = r;
        }
    }
}

static inline size_t rup(size_t b) { return (b + 255) & ~(size_t)255; }

extern "C" void kernel_launch(void* const* d_in, const int* in_sizes, int n_in,
                              void* d_out, int out_size, void* d_ws, size_t ws_size,
                              hipStream_t stream) {
    const float* x   = (const float*)d_in[0];
    const int*   ei  = (const int*)d_in[1];
    const float* Wl1 = (const float*)d_in[2];
    const float* Wr1 = (const float*)d_in[3];
    const float* b1  = (const float*)d_in[4];
    const float* Wl2 = (const float*)d_in[5];
    const float* Wr2 = (const float*)d_in[6];
    const float* b2  = (const float*)d_in[7];
    float* out = (float*)d_out;

    const int* src = ei;        // edge_index[0]
    const int* dst = ei + EE;   // edge_index[1]

    // workspace layout (256B-aligned regions)
    char* p = (char*)d_ws;
    int* binCount  = (int*)p;      p += rup((size_t)NBINS * 4);
    int* binBase   = (int*)p;      p += rup((size_t)(NBINS + 1) * 4);
    int* binCursor = (int*)p;      p += rup((size_t)NBINS * 4);
    unsigned* ebuf = (unsigned*)p; p += rup((size_t)EE * 4);
    float* agg     = (float*)p;    p += rup((size_t)NN * DD * 4);
    float* h       = out;          // layer-1 output lives in d_out

    hipMemsetAsync(binCount, 0, (size_t)NBINS * sizeof(int), stream);

    // bin build (replaces deg/scan/bucket node-CSR path)
    binhist_kernel<<<PA_BLOCKS, 256, 0, stream>>>(dst, binCount);
    binscan_kernel<<<1, 1024, 0, stream>>>(binCount, binBase, binCursor);
    binscatter_kernel<<<PA_BLOCKS, 256, 0, stream>>>(src, dst, binCursor, ebuf);

    // layer 1
    binagg_kernel<<<NBINS, 256, 0, stream>>>(x, ebuf, binBase, agg);
    layer_kernel<<<(NN + 63) / 64, 256, 0, stream>>>(agg, x, Wl1, Wr1, b1, h, 1);

    // layer 2
    binagg_kernel<<<NBINS, 256, 0, stream>>>(h, ebuf, binBase, agg);
    layer_kernel<<<(NN + 63) / 64, 256, 0, stream>>>(agg, h, Wl2, Wr2, b2, out, 0);
}

// Round 5
// 255.729 us; speedup vs baseline: 3.1654x; 3.1654x over previous
//
#include <hip/hip_runtime.h>
#include <hip/hip_bf16.h>

#define NN 50000
#define EE 800000
#define DD 64
#define NBINS 782                  // ceil(NN / 64); also the GEMM tile count
#define PA_BLOCKS 256
#define PA_CHUNK (EE / PA_BLOCKS)  // 3125

// ---------------- global per-bin histogram ---------------------------------
__global__ void binhist_kernel(const int* __restrict__ dst, int* __restrict__ binCount) {
    __shared__ int hist[NBINS];
    const int tid = threadIdx.x;
    for (int i = tid; i < NBINS; i += 256) hist[i] = 0;
    __syncthreads();
    const int e0 = blockIdx.x * PA_CHUNK;
    for (int e = e0 + tid; e < e0 + PA_CHUNK; e += 256)
        atomicAdd(&hist[dst[e] >> 6], 1);
    __syncthreads();
    for (int i = tid; i < NBINS; i += 256)
        if (hist[i]) atomicAdd(&binCount[i], hist[i]);
}

// ---------------- exclusive scan over 782 bins (one block) -----------------
__global__ void binscan_kernel(const int* __restrict__ binCount,
                               int* __restrict__ binBase, int* __restrict__ binCursor) {
    __shared__ int s[1024];
    const int tid = threadIdx.x;
    int v = (tid < NBINS) ? binCount[tid] : 0;
    s[tid] = v;
    __syncthreads();
    #pragma unroll
    for (int o = 1; o < 1024; o <<= 1) {
        int t = (tid >= o) ? s[tid - o] : 0;
        __syncthreads();
        s[tid] += t;
        __syncthreads();
    }
    if (tid < NBINS) {
        int b = s[tid] - v;        // exclusive
        binBase[tid] = b;
        binCursor[tid] = b;
    }
    if (tid == 0) binBase[NBINS] = EE;
}

// ---------------- partition edges into bin segments ------------------------
// Per-(block,bin) contiguous ranges: each 64B line of ebuf is filled by one
// block (one XCD L2) -> full-line writebacks.
__global__ void binscatter_kernel(const int* __restrict__ src, const int* __restrict__ dst,
                                  int* __restrict__ binCursor, unsigned* __restrict__ ebuf) {
    __shared__ int hist[NBINS];
    __shared__ int base[NBINS];
    const int tid = threadIdx.x;
    for (int i = tid; i < NBINS; i += 256) hist[i] = 0;
    __syncthreads();
    const int e0 = blockIdx.x * PA_CHUNK;
    for (int e = e0 + tid; e < e0 + PA_CHUNK; e += 256)
        atomicAdd(&hist[dst[e] >> 6], 1);
    __syncthreads();
    for (int i = tid; i < NBINS; i += 256) {
        int c = hist[i];
        base[i] = c ? atomicAdd(&binCursor[i], c) : 0;
        hist[i] = 0;               // reuse as local cursor
    }
    __syncthreads();
    for (int e = e0 + tid; e < e0 + PA_CHUNK; e += 256) {
        int d = dst[e];
        int b = d >> 6;
        int off = atomicAdd(&hist[b], 1);
        ebuf[base[b] + off] = ((unsigned)(d & 63) << 16) | (unsigned)src[e];
    }
}

// ---------------- node-sort within each bin -> esrc (ushort) + offs --------
// One block per bin; two passes over the bin segment (hist, then rank+write).
__global__ void binsort_kernel(const unsigned* __restrict__ ebuf,
                               const int* __restrict__ binBase,
                               unsigned short* __restrict__ esrc,
                               int* __restrict__ offs) {
    __shared__ int hist[64];
    __shared__ int cur[64];
    const int tid = threadIdx.x;
    const int b = blockIdx.x;
    const int e0 = binBase[b], e1 = binBase[b + 1];
    if (tid < 64) hist[tid] = 0;
    __syncthreads();
    for (int e = e0 + tid; e < e1; e += 256)
        atomicAdd(&hist[(ebuf[e] >> 16) & 63], 1);
    __syncthreads();
    if (tid == 0) {
        int run = e0;
        #pragma unroll
        for (int i = 0; i < 64; ++i) { int c = hist[i]; cur[i] = run; run += c; }
    }
    __syncthreads();
    if (tid < 64) {
        int node = b * 64 + tid;
        if (node <= NN) offs[node] = cur[tid];   // node==NN lands exactly at EE
    }
    __syncthreads();
    for (int e = e0 + tid; e < e1; e += 256) {
        unsigned p = ebuf[e];
        int n = (p >> 16) & 63;
        int pos = atomicAdd(&cur[n], 1);
        esrc[pos] = (unsigned short)(p & 0xFFFFu);
    }
}

// ---------------- fused layer: gather-mean -> LDS A tile -> GEMM -----------
// Block b = bin b = 64 output nodes. A = [mean_agg | self] (64x128, swizzled),
// W = [Wl;Wr] (128x64). Each thread computes a 4x4 register tile.
__launch_bounds__(256)
__global__ void fused_layer_kernel(const float* __restrict__ gsrc,
                                   const float* __restrict__ xin,
                                   const unsigned short* __restrict__ esrc,
                                   const int* __restrict__ offs,
                                   const float* __restrict__ Wl,
                                   const float* __restrict__ Wr,
                                   const float* __restrict__ bias,
                                   float* __restrict__ outp,
                                   int relu) {
    __shared__ float A[64 * 128];   // [node][k^sw], sw = (node&7)<<2
    __shared__ float W[128 * 64];   // [k][j]
    const int tid = threadIdx.x;
    const int base = blockIdx.x * 64;

    // stage W = [Wl; Wr]
    #pragma unroll
    for (int i = 0; i < 8; ++i) {
        int idx = (i * 256 + tid) * 4;       // 0..8191
        int k = idx >> 6, j = idx & 63;
        const float* sp = (k < 64) ? (Wl + k * 64 + j) : (Wr + (k - 64) * 64 + j);
        *reinterpret_cast<float4*>(&W[idx]) = *reinterpret_cast<const float4*>(sp);
    }

    // stage self rows into A[k=64..127] (coalesced)
    #pragma unroll
    for (int i = 0; i < 4; ++i) {
        int t2 = i * 256 + tid;              // 0..1023
        int n  = t2 >> 4;                    // node in tile 0..63
        int c4 = (t2 & 15) << 2;             // 0,4,...,60
        int node = base + n;
        float4 v = make_float4(0.f, 0.f, 0.f, 0.f);
        if (node < NN)
            v = *reinterpret_cast<const float4*>(xin + (size_t)node * DD + c4);
        int sw = (n & 7) << 2;
        *reinterpret_cast<float4*>(&A[n * 128 + ((64 + c4) ^ sw)]) = v;
    }

    // gather mean of neighbor rows into A[k=0..63]
    const int q    = (tid & 15) << 2;        // feature offset
    const int slot = tid >> 4;               // 0..15
    #pragma unroll
    for (int rep = 0; rep < 4; ++rep) {
        int n = slot + (rep << 4);           // 0..63
        int node = base + n;
        float ax = 0.f, ay = 0.f, az = 0.f, aw = 0.f;
        if (node < NN) {
            int ee0 = offs[node], ee1 = offs[node + 1];
            int e = ee0;
            for (; e + 3 < ee1; e += 4) {
                int s0 = esrc[e], s1 = esrc[e + 1], s2 = esrc[e + 2], s3 = esrc[e + 3];
                float4 v0 = *reinterpret_cast<const float4*>(gsrc + (size_t)s0 * DD + q);
                float4 v1 = *reinterpret_cast<const float4*>(gsrc + (size_t)s1 * DD + q);
                float4 v2 = *reinterpret_cast<const float4*>(gsrc + (size_t)s2 * DD + q);
                float4 v3 = *reinterpret_cast<const float4*>(gsrc + (size_t)s3 * DD + q);
                ax += (v0.x + v1.x) + (v2.x + v3.x);
                ay += (v0.y + v1.y) + (v2.y + v3.y);
                az += (v0.z + v1.z) + (v2.z + v3.z);
                aw += (v0.w + v1.w) + (v2.w + v3.w);
            }
            for (; e < ee1; ++e) {
                int s0 = esrc[e];
                float4 v0 = *reinterpret_cast<const float4*>(gsrc + (size_t)s0 * DD + q);
                ax += v0.x; ay += v0.y; az += v0.z; aw += v0.w;
            }
            float iv = (ee1 > ee0) ? (1.0f / (float)(ee1 - ee0)) : 0.0f;
            ax *= iv; ay *= iv; az *= iv; aw *= iv;
        }
        int sw = (n & 7) << 2;
        *reinterpret_cast<float4*>(&A[n * 128 + (q ^ sw)]) =
            make_float4(ax, ay, az, aw);
    }
    __syncthreads();

    const int tc = (tid & 15) * 4;
    const int tr = (tid >> 4) * 4;

    float acc[4][4];
    float4 bv = *reinterpret_cast<const float4*>(bias + tc);
    #pragma unroll
    for (int i = 0; i < 4; ++i) {
        acc[i][0] = bv.x; acc[i][1] = bv.y; acc[i][2] = bv.z; acc[i][3] = bv.w;
    }

    #pragma unroll 8
    for (int k = 0; k < 128; k += 4) {
        float av[4][4];
        #pragma unroll
        for (int i = 0; i < 4; ++i) {
            int row = tr + i;
            float4 a = *reinterpret_cast<const float4*>(
                &A[row * 128 + (k ^ ((row & 7) << 2))]);
            av[i][0] = a.x; av[i][1] = a.y; av[i][2] = a.z; av[i][3] = a.w;
        }
        #pragma unroll
        for (int kk = 0; kk < 4; ++kk) {
            float4 w = *reinterpret_cast<const float4*>(&W[(k + kk) * 64 + tc]);
            #pragma unroll
            for (int i = 0; i < 4; ++i) {
                acc[i][0] += av[i][kk] * w.x;
                acc[i][1] += av[i][kk] * w.y;
                acc[i][2] += av[i][kk] * w.z;
                acc[i][3] += av[i][kk] * w.w;
            }
        }
    }

    #pragma unroll
    for (int i = 0; i < 4; ++i) {
        int node = base + tr + i;
        if (node < NN) {
            float4 r = make_float4(acc[i][0], acc[i][1], acc[i][2], acc[i][3]);
            if (relu) {
                r.x = fmaxf(r.x, 0.f); r.y = fmaxf(r.y, 0.f);
                r.z = fmaxf(r.z, 0.f); r.w = fmaxf(r.w, 0.f);
            }
            *reinterpret_cast<float4*>(outp + (size_t)node * DD + tc) = r;
        }
    }
}

static inline size_t rup(size_t b) { return (b + 255) & ~(size_t)255; }

extern "C" void kernel_launch(void* const* d_in, const int* in_sizes, int n_in,
                              void* d_out, int out_size, void* d_ws, size_t ws_size,
                              hipStream_t stream) {
    const float* x   = (const float*)d_in[0];
    const int*   ei  = (const int*)d_in[1];
    const float* Wl1 = (const float*)d_in[2];
    const float* Wr1 = (const float*)d_in[3];
    const float* b1  = (const float*)d_in[4];
    const float* Wl2 = (const float*)d_in[5];
    const float* Wr2 = (const float*)d_in[6];
    const float* b2  = (const float*)d_in[7];
    float* out = (float*)d_out;

    const int* src = ei;        // edge_index[0]
    const int* dst = ei + EE;   // edge_index[1]

    // workspace layout (256B-aligned regions), ~18 MB total
    char* p = (char*)d_ws;
    int* binCount        = (int*)p;            p += rup((size_t)NBINS * 4);
    int* binBase         = (int*)p;            p += rup((size_t)(NBINS + 1) * 4);
    int* binCursor       = (int*)p;            p += rup((size_t)NBINS * 4);
    unsigned* ebuf       = (unsigned*)p;       p += rup((size_t)EE * 4);
    unsigned short* esrc = (unsigned short*)p; p += rup((size_t)EE * 2);
    int* offs            = (int*)p;            p += rup((size_t)(NN + 1) * 4);
    float* h             = (float*)p;          p += rup((size_t)NN * DD * 4);

    hipMemsetAsync(binCount, 0, (size_t)NBINS * sizeof(int), stream);

    // two-level CSR build
    binhist_kernel<<<PA_BLOCKS, 256, 0, stream>>>(dst, binCount);
    binscan_kernel<<<1, 1024, 0, stream>>>(binCount, binBase, binCursor);
    binscatter_kernel<<<PA_BLOCKS, 256, 0, stream>>>(src, dst, binCursor, ebuf);
    binsort_kernel<<<NBINS, 256, 0, stream>>>(ebuf, binBase, esrc, offs);

    // fused gather+GEMM layers
    fused_layer_kernel<<<NBINS, 256, 0, stream>>>(x, x, esrc, offs, Wl1, Wr1, b1, h, 1);
    fused_layer_kernel<<<NBINS, 256, 0, stream>>>(h, h, esrc, offs, Wl2, Wr2, b2, out, 0);
}

// Round 6
// 172.960 us; speedup vs baseline: 4.6802x; 1.4785x over previous
//
#include <hip/hip_runtime.h>
#include <hip/hip_bf16.h>

#define NN 50000
#define EE 800000
#define DD 64
#define NBINS 782                  // ceil(NN / 64)
#define PA_BLOCKS 256
#define PA_CHUNK (EE / PA_BLOCKS)  // 3125

// ---------------- global per-bin histogram ---------------------------------
__global__ void binhist_kernel(const int* __restrict__ dst, int* __restrict__ binCount) {
    __shared__ int hist[NBINS];
    const int tid = threadIdx.x;
    for (int i = tid; i < NBINS; i += 256) hist[i] = 0;
    __syncthreads();
    const int e0 = blockIdx.x * PA_CHUNK;
    for (int e = e0 + tid; e < e0 + PA_CHUNK; e += 256)
        atomicAdd(&hist[dst[e] >> 6], 1);
    __syncthreads();
    for (int i = tid; i < NBINS; i += 256)
        if (hist[i]) atomicAdd(&binCount[i], hist[i]);
}

// ---------------- exclusive scan over 782 bins (one block) -----------------
__global__ void binscan_kernel(const int* __restrict__ binCount,
                               int* __restrict__ binBase, int* __restrict__ binCursor) {
    __shared__ int s[1024];
    const int tid = threadIdx.x;
    int v = (tid < NBINS) ? binCount[tid] : 0;
    s[tid] = v;
    __syncthreads();
    #pragma unroll
    for (int o = 1; o < 1024; o <<= 1) {
        int t = (tid >= o) ? s[tid - o] : 0;
        __syncthreads();
        s[tid] += t;
        __syncthreads();
    }
    if (tid < NBINS) {
        int b = s[tid] - v;        // exclusive
        binBase[tid] = b;
        binCursor[tid] = b;
    }
    if (tid == 0) binBase[NBINS] = EE;
}

// ---------------- partition edges into bin segments ------------------------
__global__ void binscatter_kernel(const int* __restrict__ src, const int* __restrict__ dst,
                                  int* __restrict__ binCursor, unsigned* __restrict__ ebuf) {
    __shared__ int hist[NBINS];
    __shared__ int base[NBINS];
    const int tid = threadIdx.x;
    for (int i = tid; i < NBINS; i += 256) hist[i] = 0;
    __syncthreads();
    const int e0 = blockIdx.x * PA_CHUNK;
    for (int e = e0 + tid; e < e0 + PA_CHUNK; e += 256)
        atomicAdd(&hist[dst[e] >> 6], 1);
    __syncthreads();
    for (int i = tid; i < NBINS; i += 256) {
        int c = hist[i];
        base[i] = c ? atomicAdd(&binCursor[i], c) : 0;
        hist[i] = 0;               // reuse as local cursor
    }
    __syncthreads();
    for (int e = e0 + tid; e < e0 + PA_CHUNK; e += 256) {
        int d = dst[e];
        int b = d >> 6;
        int off = atomicAdd(&hist[b], 1);
        ebuf[base[b] + off] = ((unsigned)(d & 63) << 16) | (unsigned)src[e];
    }
}

// ---------------- node-sort within each bin -> esrc (ushort) + offs --------
__global__ void binsort_kernel(const unsigned* __restrict__ ebuf,
                               const int* __restrict__ binBase,
                               unsigned short* __restrict__ esrc,
                               int* __restrict__ offs) {
    __shared__ int hist[64];
    __shared__ int cur[64];
    const int tid = threadIdx.x;
    const int b = blockIdx.x;
    const int e0 = binBase[b], e1 = binBase[b + 1];
    if (tid < 64) hist[tid] = 0;
    __syncthreads();
    for (int e = e0 + tid; e < e1; e += 256)
        atomicAdd(&hist[(ebuf[e] >> 16) & 63], 1);
    __syncthreads();
    if (tid == 0) {
        int run = e0;
        #pragma unroll
        for (int i = 0; i < 64; ++i) { int c = hist[i]; cur[i] = run; run += c; }
    }
    __syncthreads();
    if (tid < 64) {
        int node = b * 64 + tid;
        if (node <= NN) offs[node] = cur[tid];   // node==NN lands exactly at EE
    }
    __syncthreads();
    for (int e = e0 + tid; e < e1; e += 256) {
        unsigned p = ebuf[e];
        int n = (p >> 16) & 63;
        int pos = atomicAdd(&cur[n], 1);
        esrc[pos] = (unsigned short)(p & 0xFFFFu);
    }
}

// ---------------- gather-aggregate: agg[n] = mean over neighbors ----------
// Register-only, 16 lanes per node (float4 each), 4-edge unroll.
// High occupancy is the point: hundreds of loads in flight per CU.
__global__ void gather_kernel(const float* __restrict__ feat,
                              const unsigned short* __restrict__ esrc,
                              const int* __restrict__ offs,
                              float* __restrict__ agg) {
    int n = blockIdx.x * 16 + (threadIdx.x >> 4);
    if (n >= NN) return;
    int q = (threadIdx.x & 15) << 2;
    int e0 = offs[n], e1 = offs[n + 1];
    float ax = 0.f, ay = 0.f, az = 0.f, aw = 0.f;
    int e = e0;
    for (; e + 3 < e1; e += 4) {
        int s0 = esrc[e], s1 = esrc[e + 1], s2 = esrc[e + 2], s3 = esrc[e + 3];
        float4 v0 = *reinterpret_cast<const float4*>(feat + (size_t)s0 * DD + q);
        float4 v1 = *reinterpret_cast<const float4*>(feat + (size_t)s1 * DD + q);
        float4 v2 = *reinterpret_cast<const float4*>(feat + (size_t)s2 * DD + q);
        float4 v3 = *reinterpret_cast<const float4*>(feat + (size_t)s3 * DD + q);
        ax += (v0.x + v1.x) + (v2.x + v3.x);
        ay += (v0.y + v1.y) + (v2.y + v3.y);
        az += (v0.z + v1.z) + (v2.z + v3.z);
        aw += (v0.w + v1.w) + (v2.w + v3.w);
    }
    for (; e < e1; ++e) {
        int s0 = esrc[e];
        float4 v0 = *reinterpret_cast<const float4*>(feat + (size_t)s0 * DD + q);
        ax += v0.x; ay += v0.y; az += v0.z; aw += v0.w;
    }
    float iv = (e1 > e0) ? (1.0f / (float)(e1 - e0)) : 0.0f;
    float4 r = make_float4(ax * iv, ay * iv, az * iv, aw * iv);
    *reinterpret_cast<float4*>(agg + (size_t)n * DD + q) = r;
}

// ---------------- SAGE layer GEMM: out = [agg | xin] @ [Wl;Wr] + b ---------
__launch_bounds__(256)
__global__ void layer_kernel(const float* __restrict__ agg,
                             const float* __restrict__ xin,
                             const float* __restrict__ Wl,
                             const float* __restrict__ Wr,
                             const float* __restrict__ bias,
                             float* __restrict__ outp,
                             int relu) {
    __shared__ float A[64 * 128];   // [node][k^sw], sw = (node&7)<<2
    __shared__ float W[128 * 64];   // [k][j]
    const int tid = threadIdx.x;
    const int base = blockIdx.x * 64;

    #pragma unroll
    for (int i = 0; i < 8; ++i) {
        int idx = (i * 256 + tid) * 4;       // 0..8191
        int k = idx >> 6, j = idx & 63;
        const float* sp = (k < 64) ? (Wl + k * 64 + j) : (Wr + (k - 64) * 64 + j);
        *reinterpret_cast<float4*>(&W[idx]) = *reinterpret_cast<const float4*>(sp);
    }

    #pragma unroll
    for (int i = 0; i < 8; ++i) {
        int t2 = i * 256 + tid;              // 0..2047
        int n  = t2 >> 5;                    // node in tile 0..63
        int c4 = (t2 & 31) * 4;              // k chunk 0,4,...,124
        int node = base + n;
        float4 v = make_float4(0.f, 0.f, 0.f, 0.f);
        if (node < NN) {
            if (c4 < 64)
                v = *reinterpret_cast<const float4*>(agg + (size_t)node * DD + c4);
            else
                v = *reinterpret_cast<const float4*>(xin + (size_t)node * DD + (c4 - 64));
        }
        int sw = (n & 7) << 2;
        *reinterpret_cast<float4*>(&A[n * 128 + (c4 ^ sw)]) = v;
    }
    __syncthreads();

    const int tc = (tid & 15) * 4;
    const int tr = (tid >> 4) * 4;

    float acc[4][4];
    float4 bv = *reinterpret_cast<const float4*>(bias + tc);
    #pragma unroll
    for (int i = 0; i < 4; ++i) {
        acc[i][0] = bv.x; acc[i][1] = bv.y; acc[i][2] = bv.z; acc[i][3] = bv.w;
    }

    #pragma unroll 8
    for (int k = 0; k < 128; k += 4) {
        float av[4][4];
        #pragma unroll
        for (int i = 0; i < 4; ++i) {
            int row = tr + i;
            float4 a = *reinterpret_cast<const float4*>(
                &A[row * 128 + (k ^ ((row & 7) << 2))]);
            av[i][0] = a.x; av[i][1] = a.y; av[i][2] = a.z; av[i][3] = a.w;
        }
        #pragma unroll
        for (int kk = 0; kk < 4; ++kk) {
            float4 w = *reinterpret_cast<const float4*>(&W[(k + kk) * 64 + tc]);
            #pragma unroll
            for (int i = 0; i < 4; ++i) {
                acc[i][0] += av[i][kk] * w.x;
                acc[i][1] += av[i][kk] * w.y;
                acc[i][2] += av[i][kk] * w.z;
                acc[i][3] += av[i][kk] * w.w;
            }
        }
    }

    #pragma unroll
    for (int i = 0; i < 4; ++i) {
        int node = base + tr + i;
        if (node < NN) {
            float4 r = make_float4(acc[i][0], acc[i][1], acc[i][2], acc[i][3]);
            if (relu) {
                r.x = fmaxf(r.x, 0.f); r.y = fmaxf(r.y, 0.f);
                r.z = fmaxf(r.z, 0.f); r.w = fmaxf(r.w, 0.f);
            }
            *reinterpret_cast<float4*>(outp + (size_t)node * DD + tc) = r;
        }
    }
}

static inline size_t rup(size_t b) { return (b + 255) & ~(size_t)255; }

extern "C" void kernel_launch(void* const* d_in, const int* in_sizes, int n_in,
                              void* d_out, int out_size, void* d_ws, size_t ws_size,
                              hipStream_t stream) {
    const float* x   = (const float*)d_in[0];
    const int*   ei  = (const int*)d_in[1];
    const float* Wl1 = (const float*)d_in[2];
    const float* Wr1 = (const float*)d_in[3];
    const float* b1  = (const float*)d_in[4];
    const float* Wl2 = (const float*)d_in[5];
    const float* Wr2 = (const float*)d_in[6];
    const float* b2  = (const float*)d_in[7];
    float* out = (float*)d_out;

    const int* src = ei;        // edge_index[0]
    const int* dst = ei + EE;   // edge_index[1]

    // workspace layout (256B-aligned regions)
    char* p = (char*)d_ws;
    int* binCount        = (int*)p;            p += rup((size_t)NBINS * 4);
    int* binBase         = (int*)p;            p += rup((size_t)(NBINS + 1) * 4);
    int* binCursor       = (int*)p;            p += rup((size_t)NBINS * 4);
    unsigned* ebuf       = (unsigned*)p;       p += rup((size_t)EE * 4);
    unsigned short* esrc = (unsigned short*)p; p += rup((size_t)EE * 2);
    int* offs            = (int*)p;            p += rup((size_t)(NN + 1) * 4);
    float* agg           = (float*)p;          p += rup((size_t)NN * DD * 4);
    float* h             = out;                // layer-1 output lives in d_out

    hipMemsetAsync(binCount, 0, (size_t)NBINS * sizeof(int), stream);

    // two-level CSR build
    binhist_kernel<<<PA_BLOCKS, 256, 0, stream>>>(dst, binCount);
    binscan_kernel<<<1, 1024, 0, stream>>>(binCount, binBase, binCursor);
    binscatter_kernel<<<PA_BLOCKS, 256, 0, stream>>>(src, dst, binCursor, ebuf);
    binsort_kernel<<<NBINS, 256, 0, stream>>>(ebuf, binBase, esrc, offs);

    // layer 1
    gather_kernel<<<(NN + 15) / 16, 256, 0, stream>>>(x, esrc, offs, agg);
    layer_kernel<<<(NN + 63) / 64, 256, 0, stream>>>(agg, x, Wl1, Wr1, b1, h, 1);

    // layer 2
    gather_kernel<<<(NN + 15) / 16, 256, 0, stream>>>(h, esrc, offs, agg);
    layer_kernel<<<(NN + 63) / 64, 256, 0, stream>>>(agg, h, Wl2, Wr2, b2, out, 0);
}

// Round 7
// 142.837 us; speedup vs baseline: 5.6672x; 1.2109x over previous
//
#include <hip/hip_runtime.h>
#include <hip/hip_bf16.h>

#define NN 50000
#define EE 800000
#define DD 64
#define NBINS 782                  // ceil(NN / 64)
#define PA_BLOCKS 256
#define PA_CHUNK (EE / PA_BLOCKS)  // 3125

// ---------------- global per-bin histogram ---------------------------------
__global__ void binhist_kernel(const int* __restrict__ dst, int* __restrict__ binCount) {
    __shared__ int hist[NBINS];
    const int tid = threadIdx.x;
    for (int i = tid; i < NBINS; i += 256) hist[i] = 0;
    __syncthreads();
    const int e0 = blockIdx.x * PA_CHUNK;
    for (int e = e0 + tid; e < e0 + PA_CHUNK; e += 256)
        atomicAdd(&hist[dst[e] >> 6], 1);
    __syncthreads();
    for (int i = tid; i < NBINS; i += 256)
        if (hist[i]) atomicAdd(&binCount[i], hist[i]);
}

// ---------------- exclusive scan over 782 bins (one block) -----------------
__global__ void binscan_kernel(const int* __restrict__ binCount,
                               int* __restrict__ binBase, int* __restrict__ binCursor) {
    __shared__ int s[1024];
    const int tid = threadIdx.x;
    int v = (tid < NBINS) ? binCount[tid] : 0;
    s[tid] = v;
    __syncthreads();
    #pragma unroll
    for (int o = 1; o < 1024; o <<= 1) {
        int t = (tid >= o) ? s[tid - o] : 0;
        __syncthreads();
        s[tid] += t;
        __syncthreads();
    }
    if (tid < NBINS) {
        int b = s[tid] - v;        // exclusive
        binBase[tid] = b;
        binCursor[tid] = b;
    }
    if (tid == 0) binBase[NBINS] = EE;
}

// ---------------- partition edges into bin segments ------------------------
__global__ void binscatter_kernel(const int* __restrict__ src, const int* __restrict__ dst,
                                  int* __restrict__ binCursor, unsigned* __restrict__ ebuf) {
    __shared__ int hist[NBINS];
    __shared__ int base[NBINS];
    const int tid = threadIdx.x;
    for (int i = tid; i < NBINS; i += 256) hist[i] = 0;
    __syncthreads();
    const int e0 = blockIdx.x * PA_CHUNK;
    for (int e = e0 + tid; e < e0 + PA_CHUNK; e += 256)
        atomicAdd(&hist[dst[e] >> 6], 1);
    __syncthreads();
    for (int i = tid; i < NBINS; i += 256) {
        int c = hist[i];
        base[i] = c ? atomicAdd(&binCursor[i], c) : 0;
        hist[i] = 0;               // reuse as local cursor
    }
    __syncthreads();
    for (int e = e0 + tid; e < e0 + PA_CHUNK; e += 256) {
        int d = dst[e];
        int b = d >> 6;
        int off = atomicAdd(&hist[b], 1);
        ebuf[base[b] + off] = ((unsigned)(d & 63) << 16) | (unsigned)src[e];
    }
}

// ---------------- node-sort within each bin -> esrc (ushort) + offs --------
__global__ void binsort_kernel(const unsigned* __restrict__ ebuf,
                               const int* __restrict__ binBase,
                               unsigned short* __restrict__ esrc,
                               int* __restrict__ offs) {
    __shared__ int hist[64];
    __shared__ int cur[64];
    const int tid = threadIdx.x;
    const int b = blockIdx.x;
    const int e0 = binBase[b], e1 = binBase[b + 1];
    if (tid < 64) hist[tid] = 0;
    __syncthreads();
    for (int e = e0 + tid; e < e1; e += 256)
        atomicAdd(&hist[(ebuf[e] >> 16) & 63], 1);
    __syncthreads();
    if (tid == 0) {
        int run = e0;
        #pragma unroll
        for (int i = 0; i < 64; ++i) { int c = hist[i]; cur[i] = run; run += c; }
    }
    __syncthreads();
    if (tid < 64) {
        int node = b * 64 + tid;
        if (node <= NN) offs[node] = cur[tid];   // node==NN lands exactly at EE
    }
    __syncthreads();
    for (int e = e0 + tid; e < e1; e += 256) {
        unsigned p = ebuf[e];
        int n = (p >> 16) & 63;
        int pos = atomicAdd(&cur[n], 1);
        esrc[pos] = (unsigned short)(p & 0xFFFFu);
    }
}

// ---------------- gather-aggregate: agg[n] = mean over neighbors ----------
__global__ void gather_kernel(const float* __restrict__ feat,
                              const unsigned short* __restrict__ esrc,
                              const int* __restrict__ offs,
                              float* __restrict__ agg) {
    int n = blockIdx.x * 16 + (threadIdx.x >> 4);
    if (n >= NN) return;
    int q = (threadIdx.x & 15) << 2;
    int e0 = offs[n], e1 = offs[n + 1];
    float ax = 0.f, ay = 0.f, az = 0.f, aw = 0.f;
    int e = e0;
    for (; e + 3 < e1; e += 4) {
        int s0 = esrc[e], s1 = esrc[e + 1], s2 = esrc[e + 2], s3 = esrc[e + 3];
        float4 v0 = *reinterpret_cast<const float4*>(feat + (size_t)s0 * DD + q);
        float4 v1 = *reinterpret_cast<const float4*>(feat + (size_t)s1 * DD + q);
        float4 v2 = *reinterpret_cast<const float4*>(feat + (size_t)s2 * DD + q);
        float4 v3 = *reinterpret_cast<const float4*>(feat + (size_t)s3 * DD + q);
        ax += (v0.x + v1.x) + (v2.x + v3.x);
        ay += (v0.y + v1.y) + (v2.y + v3.y);
        az += (v0.z + v1.z) + (v2.z + v3.z);
        aw += (v0.w + v1.w) + (v2.w + v3.w);
    }
    for (; e < e1; ++e) {
        int s0 = esrc[e];
        float4 v0 = *reinterpret_cast<const float4*>(feat + (size_t)s0 * DD + q);
        ax += v0.x; ay += v0.y; az += v0.z; aw += v0.w;
    }
    float iv = (e1 > e0) ? (1.0f / (float)(e1 - e0)) : 0.0f;
    float4 r = make_float4(ax * iv, ay * iv, az * iv, aw * iv);
    *reinterpret_cast<float4*>(agg + (size_t)n * DD + q) = r;
}

// ---------------- SAGE layer GEMM, split-K two-pass ------------------------
// Pass 0: acc += aggTile @ Wl ; Pass 1: acc += xTile @ Wr. One 16KB A buffer
// + one 16KB W buffer reused across passes -> 32KB LDS -> 4+ blocks/CU.
__launch_bounds__(256, 4)
__global__ void layer_kernel(const float* __restrict__ agg,
                             const float* __restrict__ xin,
                             const float* __restrict__ Wl,
                             const float* __restrict__ Wr,
                             const float* __restrict__ bias,
                             float* __restrict__ outp,
                             int relu) {
    __shared__ float A[64 * 64];    // [node][k ^ ((node&15)<<2)]
    __shared__ float W[64 * 64];    // [k][j]
    const int tid = threadIdx.x;
    const int base = blockIdx.x * 64;
    const int tc = (tid & 15) * 4;  // col base
    const int tr = (tid >> 4) * 4;  // node base in tile

    float acc[4][4];
    float4 bv = *reinterpret_cast<const float4*>(bias + tc);
    #pragma unroll
    for (int i = 0; i < 4; ++i) {
        acc[i][0] = bv.x; acc[i][1] = bv.y; acc[i][2] = bv.z; acc[i][3] = bv.w;
    }

    for (int pass = 0; pass < 2; ++pass) {
        const float* Wsrc = pass ? Wr : Wl;
        const float* Asrc = pass ? xin : agg;
        if (pass) __syncthreads();          // all reads of previous tiles done

        // stage W (64x64 row-major, contiguous)
        #pragma unroll
        for (int i = 0; i < 4; ++i) {
            int idx = (i * 256 + tid) * 4;  // 0..4095
            *reinterpret_cast<float4*>(&W[idx]) =
                *reinterpret_cast<const float4*>(Wsrc + idx);
        }
        // stage A tile (64 nodes x 64 feats, swizzled)
        #pragma unroll
        for (int i = 0; i < 4; ++i) {
            int t2 = i * 256 + tid;         // 0..1023
            int n  = t2 >> 4;               // 0..63
            int c4 = (t2 & 15) << 2;        // 0,4,...,60
            int node = base + n;
            float4 v = make_float4(0.f, 0.f, 0.f, 0.f);
            if (node < NN)
                v = *reinterpret_cast<const float4*>(Asrc + (size_t)node * DD + c4);
            *reinterpret_cast<float4*>(&A[n * 64 + (c4 ^ ((n & 15) << 2))]) = v;
        }
        __syncthreads();

        #pragma unroll 4
        for (int k = 0; k < 64; k += 4) {
            float av[4][4];
            #pragma unroll
            for (int i = 0; i < 4; ++i) {
                int row = tr + i;
                float4 a = *reinterpret_cast<const float4*>(
                    &A[row * 64 + (k ^ ((row & 15) << 2))]);
                av[i][0] = a.x; av[i][1] = a.y; av[i][2] = a.z; av[i][3] = a.w;
            }
            #pragma unroll
            for (int kk = 0; kk < 4; ++kk) {
                float4 w = *reinterpret_cast<const float4*>(&W[(k + kk) * 64 + tc]);
                #pragma unroll
                for (int i = 0; i < 4; ++i) {
                    acc[i][0] += av[i][kk] * w.x;
                    acc[i][1] += av[i][kk] * w.y;
                    acc[i][2] += av[i][kk] * w.z;
                    acc[i][3] += av[i][kk] * w.w;
                }
            }
        }
    }

    #pragma unroll
    for (int i = 0; i < 4; ++i) {
        int node = base + tr + i;
        if (node < NN) {
            float4 r = make_float4(acc[i][0], acc[i][1], acc[i][2], acc[i][3]);
            if (relu) {
                r.x = fmaxf(r.x, 0.f); r.y = fmaxf(r.y, 0.f);
                r.z = fmaxf(r.z, 0.f); r.w = fmaxf(r.w, 0.f);
            }
            *reinterpret_cast<float4*>(outp + (size_t)node * DD + tc) = r;
        }
    }
}

static inline size_t rup(size_t b) { return (b + 255) & ~(size_t)255; }

extern "C" void kernel_launch(void* const* d_in, const int* in_sizes, int n_in,
                              void* d_out, int out_size, void* d_ws, size_t ws_size,
                              hipStream_t stream) {
    const float* x   = (const float*)d_in[0];
    const int*   ei  = (const int*)d_in[1];
    const float* Wl1 = (const float*)d_in[2];
    const float* Wr1 = (const float*)d_in[3];
    const float* b1  = (const float*)d_in[4];
    const float* Wl2 = (const float*)d_in[5];
    const float* Wr2 = (const float*)d_in[6];
    const float* b2  = (const float*)d_in[7];
    float* out = (float*)d_out;

    const int* src = ei;        // edge_index[0]
    const int* dst = ei + EE;   // edge_index[1]

    // workspace layout (256B-aligned regions)
    char* p = (char*)d_ws;
    int* binCount        = (int*)p;            p += rup((size_t)NBINS * 4);
    int* binBase         = (int*)p;            p += rup((size_t)(NBINS + 1) * 4);
    int* binCursor       = (int*)p;            p += rup((size_t)NBINS * 4);
    unsigned* ebuf       = (unsigned*)p;       p += rup((size_t)EE * 4);
    unsigned short* esrc = (unsigned short*)p; p += rup((size_t)EE * 2);
    int* offs            = (int*)p;            p += rup((size_t)(NN + 1) * 4);
    float* agg           = (float*)p;          p += rup((size_t)NN * DD * 4);
    float* h             = out;                // layer-1 output lives in d_out

    hipMemsetAsync(binCount, 0, (size_t)NBINS * sizeof(int), stream);

    // two-level CSR build
    binhist_kernel<<<PA_BLOCKS, 256, 0, stream>>>(dst, binCount);
    binscan_kernel<<<1, 1024, 0, stream>>>(binCount, binBase, binCursor);
    binscatter_kernel<<<PA_BLOCKS, 256, 0, stream>>>(src, dst, binCursor, ebuf);
    binsort_kernel<<<NBINS, 256, 0, stream>>>(ebuf, binBase, esrc, offs);

    // layer 1
    gather_kernel<<<(NN + 15) / 16, 256, 0, stream>>>(x, esrc, offs, agg);
    layer_kernel<<<(NN + 63) / 64, 256, 0, stream>>>(agg, x, Wl1, Wr1, b1, h, 1);

    // layer 2
    gather_kernel<<<(NN + 15) / 16, 256, 0, stream>>>(h, esrc, offs, agg);
    layer_kernel<<<(NN + 63) / 64, 256, 0, stream>>>(agg, h, Wl2, Wr2, b2, out, 0);
}

// Round 8
// 140.954 us; speedup vs baseline: 5.7429x; 1.0134x over previous
//
#include <hip/hip_runtime.h>
#include <hip/hip_bf16.h>

#define NN 50000
#define EE 800000
#define DD 64
#define NBINS 782                  // ceil(NN / 64)
#define PA_BLOCKS 256
#define PA_CHUNK (EE / PA_BLOCKS)  // 3125

// ---------------- per-block bin histogram -> partial[block][bin] -----------
// Non-atomic global writes; every cell written -> no init/memset needed.
__global__ void binhist_kernel(const int* __restrict__ dst, int* __restrict__ partial) {
    __shared__ int hist[NBINS];
    const int tid = threadIdx.x;
    for (int i = tid; i < NBINS; i += 256) hist[i] = 0;
    __syncthreads();
    const int e0 = blockIdx.x * PA_CHUNK;
    for (int e = e0 + tid; e < e0 + PA_CHUNK; e += 256)
        atomicAdd(&hist[dst[e] >> 6], 1);
    __syncthreads();
    int* row = partial + (size_t)blockIdx.x * NBINS;
    for (int i = tid; i < NBINS; i += 256) row[i] = hist[i];
}

// ---------------- column-sum partials -> binCount (no atomics) -------------
__global__ void binsum_kernel(const int* __restrict__ partial, int* __restrict__ binCount) {
    int j = blockIdx.x * 256 + threadIdx.x;
    if (j < NBINS) {
        int s = 0;
        #pragma unroll 8
        for (int b = 0; b < PA_BLOCKS; ++b)
            s += partial[(size_t)b * NBINS + j];
        binCount[j] = s;
    }
}

// ---------------- exclusive scan over 782 bins (one block) -----------------
__global__ void binscan_kernel(const int* __restrict__ binCount,
                               int* __restrict__ binBase, int* __restrict__ binCursor) {
    __shared__ int s[1024];
    const int tid = threadIdx.x;
    int v = (tid < NBINS) ? binCount[tid] : 0;
    s[tid] = v;
    __syncthreads();
    #pragma unroll
    for (int o = 1; o < 1024; o <<= 1) {
        int t = (tid >= o) ? s[tid - o] : 0;
        __syncthreads();
        s[tid] += t;
        __syncthreads();
    }
    if (tid < NBINS) {
        int b = s[tid] - v;        // exclusive
        binBase[tid] = b;
        binCursor[tid] = b;
    }
    if (tid == 0) binBase[NBINS] = EE;
}

// ---------------- partition edges into bin segments ------------------------
__global__ void binscatter_kernel(const int* __restrict__ src, const int* __restrict__ dst,
                                  int* __restrict__ binCursor, unsigned* __restrict__ ebuf) {
    __shared__ int hist[NBINS];
    __shared__ int base[NBINS];
    const int tid = threadIdx.x;
    for (int i = tid; i < NBINS; i += 256) hist[i] = 0;
    __syncthreads();
    const int e0 = blockIdx.x * PA_CHUNK;
    for (int e = e0 + tid; e < e0 + PA_CHUNK; e += 256)
        atomicAdd(&hist[dst[e] >> 6], 1);
    __syncthreads();
    for (int i = tid; i < NBINS; i += 256) {
        int c = hist[i];
        base[i] = c ? atomicAdd(&binCursor[i], c) : 0;
        hist[i] = 0;               // reuse as local cursor
    }
    __syncthreads();
    for (int e = e0 + tid; e < e0 + PA_CHUNK; e += 256) {
        int d = dst[e];
        int b = d >> 6;
        int off = atomicAdd(&hist[b], 1);
        ebuf[base[b] + off] = ((unsigned)(d & 63) << 16) | (unsigned)src[e];
    }
}

// ---------------- node-sort within each bin -> esrc (ushort) + offs --------
__global__ void binsort_kernel(const unsigned* __restrict__ ebuf,
                               const int* __restrict__ binBase,
                               unsigned short* __restrict__ esrc,
                               int* __restrict__ offs) {
    __shared__ int hist[64];
    __shared__ int cur[64];
    const int tid = threadIdx.x;
    const int b = blockIdx.x;
    const int e0 = binBase[b], e1 = binBase[b + 1];
    if (tid < 64) hist[tid] = 0;
    __syncthreads();
    for (int e = e0 + tid; e < e1; e += 256)
        atomicAdd(&hist[(ebuf[e] >> 16) & 63], 1);
    __syncthreads();
    if (tid == 0) {
        int run = e0;
        #pragma unroll
        for (int i = 0; i < 64; ++i) { int c = hist[i]; cur[i] = run; run += c; }
    }
    __syncthreads();
    if (tid < 64) {
        int node = b * 64 + tid;
        if (node <= NN) offs[node] = cur[tid];   // node==NN lands exactly at EE
    }
    __syncthreads();
    for (int e = e0 + tid; e < e1; e += 256) {
        unsigned p = ebuf[e];
        int n = (p >> 16) & 63;
        int pos = atomicAdd(&cur[n], 1);
        esrc[pos] = (unsigned short)(p & 0xFFFFu);
    }
}

// ---------------- gather-aggregate: agg[n] = mean over neighbors ----------
__global__ void gather_kernel(const float* __restrict__ feat,
                              const unsigned short* __restrict__ esrc,
                              const int* __restrict__ offs,
                              float* __restrict__ agg) {
    int n = blockIdx.x * 16 + (threadIdx.x >> 4);
    if (n >= NN) return;
    int q = (threadIdx.x & 15) << 2;
    int e0 = offs[n], e1 = offs[n + 1];
    float ax = 0.f, ay = 0.f, az = 0.f, aw = 0.f;
    int e = e0;
    for (; e + 3 < e1; e += 4) {
        int s0 = esrc[e], s1 = esrc[e + 1], s2 = esrc[e + 2], s3 = esrc[e + 3];
        float4 v0 = *reinterpret_cast<const float4*>(feat + (size_t)s0 * DD + q);
        float4 v1 = *reinterpret_cast<const float4*>(feat + (size_t)s1 * DD + q);
        float4 v2 = *reinterpret_cast<const float4*>(feat + (size_t)s2 * DD + q);
        float4 v3 = *reinterpret_cast<const float4*>(feat + (size_t)s3 * DD + q);
        ax += (v0.x + v1.x) + (v2.x + v3.x);
        ay += (v0.y + v1.y) + (v2.y + v3.y);
        az += (v0.z + v1.z) + (v2.z + v3.z);
        aw += (v0.w + v1.w) + (v2.w + v3.w);
    }
    for (; e < e1; ++e) {
        int s0 = esrc[e];
        float4 v0 = *reinterpret_cast<const float4*>(feat + (size_t)s0 * DD + q);
        ax += v0.x; ay += v0.y; az += v0.z; aw += v0.w;
    }
    float iv = (e1 > e0) ? (1.0f / (float)(e1 - e0)) : 0.0f;
    float4 r = make_float4(ax * iv, ay * iv, az * iv, aw * iv);
    *reinterpret_cast<float4*>(agg + (size_t)n * DD + q) = r;
}

// ---------------- SAGE layer GEMM, split-K two-pass ------------------------
__launch_bounds__(256, 4)
__global__ void layer_kernel(const float* __restrict__ agg,
                             const float* __restrict__ xin,
                             const float* __restrict__ Wl,
                             const float* __restrict__ Wr,
                             const float* __restrict__ bias,
                             float* __restrict__ outp,
                             int relu) {
    __shared__ float A[64 * 64];    // [node][k ^ ((node&15)<<2)]
    __shared__ float W[64 * 64];    // [k][j]
    const int tid = threadIdx.x;
    const int base = blockIdx.x * 64;
    const int tc = (tid & 15) * 4;  // col base
    const int tr = (tid >> 4) * 4;  // node base in tile

    float acc[4][4];
    float4 bv = *reinterpret_cast<const float4*>(bias + tc);
    #pragma unroll
    for (int i = 0; i < 4; ++i) {
        acc[i][0] = bv.x; acc[i][1] = bv.y; acc[i][2] = bv.z; acc[i][3] = bv.w;
    }

    for (int pass = 0; pass < 2; ++pass) {
        const float* Wsrc = pass ? Wr : Wl;
        const float* Asrc = pass ? xin : agg;
        if (pass) __syncthreads();          // all reads of previous tiles done

        // stage W (64x64 row-major, contiguous)
        #pragma unroll
        for (int i = 0; i < 4; ++i) {
            int idx = (i * 256 + tid) * 4;  // 0..4095
            *reinterpret_cast<float4*>(&W[idx]) =
                *reinterpret_cast<const float4*>(Wsrc + idx);
        }
        // stage A tile (64 nodes x 64 feats, swizzled)
        #pragma unroll
        for (int i = 0; i < 4; ++i) {
            int t2 = i * 256 + tid;         // 0..1023
            int n  = t2 >> 4;               // 0..63
            int c4 = (t2 & 15) << 2;        // 0,4,...,60
            int node = base + n;
            float4 v = make_float4(0.f, 0.f, 0.f, 0.f);
            if (node < NN)
                v = *reinterpret_cast<const float4*>(Asrc + (size_t)node * DD + c4);
            *reinterpret_cast<float4*>(&A[n * 64 + (c4 ^ ((n & 15) << 2))]) = v;
        }
        __syncthreads();

        #pragma unroll 4
        for (int k = 0; k < 64; k += 4) {
            float av[4][4];
            #pragma unroll
            for (int i = 0; i < 4; ++i) {
                int row = tr + i;
                float4 a = *reinterpret_cast<const float4*>(
                    &A[row * 64 + (k ^ ((row & 15) << 2))]);
                av[i][0] = a.x; av[i][1] = a.y; av[i][2] = a.z; av[i][3] = a.w;
            }
            #pragma unroll
            for (int kk = 0; kk < 4; ++kk) {
                float4 w = *reinterpret_cast<const float4*>(&W[(k + kk) * 64 + tc]);
                #pragma unroll
                for (int i = 0; i < 4; ++i) {
                    acc[i][0] += av[i][kk] * w.x;
                    acc[i][1] += av[i][kk] * w.y;
                    acc[i][2] += av[i][kk] * w.z;
                    acc[i][3] += av[i][kk] * w.w;
                }
            }
        }
    }

    #pragma unroll
    for (int i = 0; i < 4; ++i) {
        int node = base + tr + i;
        if (node < NN) {
            float4 r = make_float4(acc[i][0], acc[i][1], acc[i][2], acc[i][3]);
            if (relu) {
                r.x = fmaxf(r.x, 0.f); r.y = fmaxf(r.y, 0.f);
                r.z = fmaxf(r.z, 0.f); r.w = fmaxf(r.w, 0.f);
            }
            *reinterpret_cast<float4*>(outp + (size_t)node * DD + tc) = r;
        }
    }
}

static inline size_t rup(size_t b) { return (b + 255) & ~(size_t)255; }

extern "C" void kernel_launch(void* const* d_in, const int* in_sizes, int n_in,
                              void* d_out, int out_size, void* d_ws, size_t ws_size,
                              hipStream_t stream) {
    const float* x   = (const float*)d_in[0];
    const int*   ei  = (const int*)d_in[1];
    const float* Wl1 = (const float*)d_in[2];
    const float* Wr1 = (const float*)d_in[3];
    const float* b1  = (const float*)d_in[4];
    const float* Wl2 = (const float*)d_in[5];
    const float* Wr2 = (const float*)d_in[6];
    const float* b2  = (const float*)d_in[7];
    float* out = (float*)d_out;

    const int* src = ei;        // edge_index[0]
    const int* dst = ei + EE;   // edge_index[1]

    // workspace layout (256B-aligned regions)
    char* p = (char*)d_ws;
    int* partial         = (int*)p;            p += rup((size_t)PA_BLOCKS * NBINS * 4);
    int* binCount        = (int*)p;            p += rup((size_t)NBINS * 4);
    int* binBase         = (int*)p;            p += rup((size_t)(NBINS + 1) * 4);
    int* binCursor       = (int*)p;            p += rup((size_t)NBINS * 4);
    unsigned* ebuf       = (unsigned*)p;       p += rup((size_t)EE * 4);
    unsigned short* esrc = (unsigned short*)p; p += rup((size_t)EE * 2);
    int* offs            = (int*)p;            p += rup((size_t)(NN + 1) * 4);
    float* agg           = (float*)p;          p += rup((size_t)NN * DD * 4);
    float* h             = out;                // layer-1 output lives in d_out

    // two-level CSR build (no memset anywhere)
    binhist_kernel<<<PA_BLOCKS, 256, 0, stream>>>(dst, partial);
    binsum_kernel<<<(NBINS + 255) / 256, 256, 0, stream>>>(partial, binCount);
    binscan_kernel<<<1, 1024, 0, stream>>>(binCount, binBase, binCursor);
    binscatter_kernel<<<PA_BLOCKS, 256, 0, stream>>>(src, dst, binCursor, ebuf);
    binsort_kernel<<<NBINS, 256, 0, stream>>>(ebuf, binBase, esrc, offs);

    // layer 1
    gather_kernel<<<(NN + 15) / 16, 256, 0, stream>>>(x, esrc, offs, agg);
    layer_kernel<<<(NN + 63) / 64, 256, 0, stream>>>(agg, x, Wl1, Wr1, b1, h, 1);

    // layer 2
    gather_kernel<<<(NN + 15) / 16, 256, 0, stream>>>(h, esrc, offs, agg);
    layer_kernel<<<(NN + 63) / 64, 256, 0, stream>>>(agg, h, Wl2, Wr2, b2, out, 0);
}

// Round 9
// 137.689 us; speedup vs baseline: 5.8791x; 1.0237x over previous
//
#include <hip/hip_runtime.h>
#include <hip/hip_bf16.h>

#define NN 50000
#define EE 800000
#define DD 64
#define NBINS 782                  // ceil(NN / 64)
#define PA_BLOCKS 256
#define PA_CHUNK (EE / PA_BLOCKS)  // 3125

// ---------------- per-block bin histogram -> partial[block][bin] -----------
__global__ void binhist_kernel(const int* __restrict__ dst, int* __restrict__ partial) {
    __shared__ int hist[NBINS];
    const int tid = threadIdx.x;
    for (int i = tid; i < NBINS; i += 256) hist[i] = 0;
    __syncthreads();
    const int e0 = blockIdx.x * PA_CHUNK;
    for (int e = e0 + tid; e < e0 + PA_CHUNK; e += 256)
        atomicAdd(&hist[dst[e] >> 6], 1);
    __syncthreads();
    int* row = partial + (size_t)blockIdx.x * NBINS;
    for (int i = tid; i < NBINS; i += 256) row[i] = hist[i];
}

// ---------------- column-sum partials -> binCount (no atomics) -------------
__global__ void binsum_kernel(const int* __restrict__ partial, int* __restrict__ binCount) {
    int j = blockIdx.x * 256 + threadIdx.x;
    if (j < NBINS) {
        int s = 0;
        #pragma unroll 8
        for (int b = 0; b < PA_BLOCKS; ++b)
            s += partial[(size_t)b * NBINS + j];
        binCount[j] = s;
    }
}

// ---------------- exclusive scan over 782 bins (one block) -----------------
__global__ void binscan_kernel(const int* __restrict__ binCount,
                               int* __restrict__ binBase, int* __restrict__ binCursor) {
    __shared__ int s[1024];
    const int tid = threadIdx.x;
    int v = (tid < NBINS) ? binCount[tid] : 0;
    s[tid] = v;
    __syncthreads();
    #pragma unroll
    for (int o = 1; o < 1024; o <<= 1) {
        int t = (tid >= o) ? s[tid - o] : 0;
        __syncthreads();
        s[tid] += t;
        __syncthreads();
    }
    if (tid < NBINS) {
        int b = s[tid] - v;        // exclusive
        binBase[tid] = b;
        binCursor[tid] = b;
    }
    if (tid == 0) binBase[NBINS] = EE;
}

// ---------------- partition edges into bin segments ------------------------
__global__ void binscatter_kernel(const int* __restrict__ src, const int* __restrict__ dst,
                                  int* __restrict__ binCursor, unsigned* __restrict__ ebuf) {
    __shared__ int hist[NBINS];
    __shared__ int base[NBINS];
    const int tid = threadIdx.x;
    for (int i = tid; i < NBINS; i += 256) hist[i] = 0;
    __syncthreads();
    const int e0 = blockIdx.x * PA_CHUNK;
    for (int e = e0 + tid; e < e0 + PA_CHUNK; e += 256)
        atomicAdd(&hist[dst[e] >> 6], 1);
    __syncthreads();
    for (int i = tid; i < NBINS; i += 256) {
        int c = hist[i];
        base[i] = c ? atomicAdd(&binCursor[i], c) : 0;
        hist[i] = 0;               // reuse as local cursor
    }
    __syncthreads();
    for (int e = e0 + tid; e < e0 + PA_CHUNK; e += 256) {
        int d = dst[e];
        int b = d >> 6;
        int off = atomicAdd(&hist[b], 1);
        ebuf[base[b] + off] = ((unsigned)(d & 63) << 16) | (unsigned)src[e];
    }
}

// ---------------- node-sort within each bin -> esrc (ushort) + offs --------
__global__ void binsort_kernel(const unsigned* __restrict__ ebuf,
                               const int* __restrict__ binBase,
                               unsigned short* __restrict__ esrc,
                               int* __restrict__ offs) {
    __shared__ int hist[64];
    __shared__ int cur[64];
    const int tid = threadIdx.x;
    const int b = blockIdx.x;
    const int e0 = binBase[b], e1 = binBase[b + 1];
    if (tid < 64) hist[tid] = 0;
    __syncthreads();
    for (int e = e0 + tid; e < e1; e += 256)
        atomicAdd(&hist[(ebuf[e] >> 16) & 63], 1);
    __syncthreads();
    if (tid == 0) {
        int run = e0;
        #pragma unroll
        for (int i = 0; i < 64; ++i) { int c = hist[i]; cur[i] = run; run += c; }
    }
    __syncthreads();
    if (tid < 64) {
        int node = b * 64 + tid;
        if (node <= NN) offs[node] = cur[tid];   // node==NN lands exactly at EE
    }
    __syncthreads();
    for (int e = e0 + tid; e < e1; e += 256) {
        unsigned p = ebuf[e];
        int n = (p >> 16) & 63;
        int pos = atomicAdd(&cur[n], 1);
        esrc[pos] = (unsigned short)(p & 0xFFFFu);
    }
}

// ---------------- fused layer: gather-mean -> GEMM(Wl) ; self -> GEMM(Wr) --
// 32KB LDS (16KB A + 16KB W), __launch_bounds__(256,4) -> 4 blocks/CU,
// 16 waves/CU for the latency-bound gather phase (round-5 failed at 64KB/8%).
__launch_bounds__(256, 4)
__global__ void fused_layer_kernel(const float* __restrict__ gsrc,
                                   const float* __restrict__ xin,
                                   const unsigned short* __restrict__ esrc,
                                   const int* __restrict__ offs,
                                   const float* __restrict__ Wl,
                                   const float* __restrict__ Wr,
                                   const float* __restrict__ bias,
                                   float* __restrict__ outp,
                                   int relu) {
    __shared__ float A[64 * 64];    // [n][k ^ ((n&15)<<2)]
    __shared__ float W[64 * 64];    // [k][j]
    const int tid = threadIdx.x;
    const int base = blockIdx.x * 64;
    const int tc = (tid & 15) * 4;
    const int tr = (tid >> 4) * 4;

    float acc[4][4];
    float4 bv = *reinterpret_cast<const float4*>(bias + tc);
    #pragma unroll
    for (int i = 0; i < 4; ++i) {
        acc[i][0] = bv.x; acc[i][1] = bv.y; acc[i][2] = bv.z; acc[i][3] = bv.w;
    }

    // ===== pass 0: A = gathered neighbor means, W = Wl =====
    #pragma unroll
    for (int i = 0; i < 4; ++i) {
        int idx = (i * 256 + tid) * 4;
        *reinterpret_cast<float4*>(&W[idx]) =
            *reinterpret_cast<const float4*>(Wl + idx);
    }
    const int q = (tid & 15) << 2;   // feature chunk
    const int slot = tid >> 4;       // 0..15
    #pragma unroll
    for (int rep = 0; rep < 4; ++rep) {
        int n = slot + (rep << 4);   // 0..63
        int node = base + n;
        float ax = 0.f, ay = 0.f, az = 0.f, aw = 0.f;
        if (node < NN) {
            int e0 = offs[node], e1 = offs[node + 1];
            int e = e0;
            for (; e + 3 < e1; e += 4) {
                int s0 = esrc[e], s1 = esrc[e + 1], s2 = esrc[e + 2], s3 = esrc[e + 3];
                float4 v0 = *reinterpret_cast<const float4*>(gsrc + (size_t)s0 * DD + q);
                float4 v1 = *reinterpret_cast<const float4*>(gsrc + (size_t)s1 * DD + q);
                float4 v2 = *reinterpret_cast<const float4*>(gsrc + (size_t)s2 * DD + q);
                float4 v3 = *reinterpret_cast<const float4*>(gsrc + (size_t)s3 * DD + q);
                ax += (v0.x + v1.x) + (v2.x + v3.x);
                ay += (v0.y + v1.y) + (v2.y + v3.y);
                az += (v0.z + v1.z) + (v2.z + v3.z);
                aw += (v0.w + v1.w) + (v2.w + v3.w);
            }
            for (; e < e1; ++e) {
                int s0 = esrc[e];
                float4 v0 = *reinterpret_cast<const float4*>(gsrc + (size_t)s0 * DD + q);
                ax += v0.x; ay += v0.y; az += v0.z; aw += v0.w;
            }
            float iv = (e1 > e0) ? (1.0f / (float)(e1 - e0)) : 0.0f;
            ax *= iv; ay *= iv; az *= iv; aw *= iv;
        }
        *reinterpret_cast<float4*>(&A[n * 64 + (q ^ ((n & 15) << 2))]) =
            make_float4(ax, ay, az, aw);
    }
    __syncthreads();

    #pragma unroll 4
    for (int k = 0; k < 64; k += 4) {
        float av[4][4];
        #pragma unroll
        for (int i = 0; i < 4; ++i) {
            int row = tr + i;
            float4 a = *reinterpret_cast<const float4*>(
                &A[row * 64 + (k ^ ((row & 15) << 2))]);
            av[i][0] = a.x; av[i][1] = a.y; av[i][2] = a.z; av[i][3] = a.w;
        }
        #pragma unroll
        for (int kk = 0; kk < 4; ++kk) {
            float4 w = *reinterpret_cast<const float4*>(&W[(k + kk) * 64 + tc]);
            #pragma unroll
            for (int i = 0; i < 4; ++i) {
                acc[i][0] += av[i][kk] * w.x;
                acc[i][1] += av[i][kk] * w.y;
                acc[i][2] += av[i][kk] * w.z;
                acc[i][3] += av[i][kk] * w.w;
            }
        }
    }
    __syncthreads();     // done reading A/W; safe to restage

    // ===== pass 1: A = self rows (coalesced), W = Wr =====
    #pragma unroll
    for (int i = 0; i < 4; ++i) {
        int idx = (i * 256 + tid) * 4;
        *reinterpret_cast<float4*>(&W[idx]) =
            *reinterpret_cast<const float4*>(Wr + idx);
    }
    #pragma unroll
    for (int i = 0; i < 4; ++i) {
        int t2 = i * 256 + tid;
        int n  = t2 >> 4;
        int c4 = (t2 & 15) << 2;
        int node = base + n;
        float4 v = make_float4(0.f, 0.f, 0.f, 0.f);
        if (node < NN)
            v = *reinterpret_cast<const float4*>(xin + (size_t)node * DD + c4);
        *reinterpret_cast<float4*>(&A[n * 64 + (c4 ^ ((n & 15) << 2))]) = v;
    }
    __syncthreads();

    #pragma unroll 4
    for (int k = 0; k < 64; k += 4) {
        float av[4][4];
        #pragma unroll
        for (int i = 0; i < 4; ++i) {
            int row = tr + i;
            float4 a = *reinterpret_cast<const float4*>(
                &A[row * 64 + (k ^ ((row & 15) << 2))]);
            av[i][0] = a.x; av[i][1] = a.y; av[i][2] = a.z; av[i][3] = a.w;
        }
        #pragma unroll
        for (int kk = 0; kk < 4; ++kk) {
            float4 w = *reinterpret_cast<const float4*>(&W[(k + kk) * 64 + tc]);
            #pragma unroll
            for (int i = 0; i < 4; ++i) {
                acc[i][0] += av[i][kk] * w.x;
                acc[i][1] += av[i][kk] * w.y;
                acc[i][2] += av[i][kk] * w.z;
                acc[i][3] += av[i][kk] * w.w;
            }
        }
    }

    #pragma unroll
    for (int i = 0; i < 4; ++i) {
        int node = base + tr + i;
        if (node < NN) {
            float4 r = make_float4(acc[i][0], acc[i][1], acc[i][2], acc[i][3]);
            if (relu) {
                r.x = fmaxf(r.x, 0.f); r.y = fmaxf(r.y, 0.f);
                r.z = fmaxf(r.z, 0.f); r.w = fmaxf(r.w, 0.f);
            }
            *reinterpret_cast<float4*>(outp + (size_t)node * DD + tc) = r;
        }
    }
}

static inline size_t rup(size_t b) { return (b + 255) & ~(size_t)255; }

extern "C" void kernel_launch(void* const* d_in, const int* in_sizes, int n_in,
                              void* d_out, int out_size, void* d_ws, size_t ws_size,
                              hipStream_t stream) {
    const float* x   = (const float*)d_in[0];
    const int*   ei  = (const int*)d_in[1];
    const float* Wl1 = (const float*)d_in[2];
    const float* Wr1 = (const float*)d_in[3];
    const float* b1  = (const float*)d_in[4];
    const float* Wl2 = (const float*)d_in[5];
    const float* Wr2 = (const float*)d_in[6];
    const float* b2  = (const float*)d_in[7];
    float* out = (float*)d_out;

    const int* src = ei;        // edge_index[0]
    const int* dst = ei + EE;   // edge_index[1]

    // workspace layout (256B-aligned regions)
    char* p = (char*)d_ws;
    int* partial         = (int*)p;            p += rup((size_t)PA_BLOCKS * NBINS * 4);
    int* binCount        = (int*)p;            p += rup((size_t)NBINS * 4);
    int* binBase         = (int*)p;            p += rup((size_t)(NBINS + 1) * 4);
    int* binCursor       = (int*)p;            p += rup((size_t)NBINS * 4);
    unsigned* ebuf       = (unsigned*)p;       p += rup((size_t)EE * 4);
    unsigned short* esrc = (unsigned short*)p; p += rup((size_t)EE * 2);
    int* offs            = (int*)p;            p += rup((size_t)(NN + 1) * 4);
    float* h             = (float*)p;          p += rup((size_t)NN * DD * 4);
    // h must be workspace (NOT d_out): layer-2 gathers random h rows across
    // tiles while writing d_out rows -> aliasing would race.

    // two-level CSR build (no memset anywhere)
    binhist_kernel<<<PA_BLOCKS, 256, 0, stream>>>(dst, partial);
    binsum_kernel<<<(NBINS + 255) / 256, 256, 0, stream>>>(partial, binCount);
    binscan_kernel<<<1, 1024, 0, stream>>>(binCount, binBase, binCursor);
    binscatter_kernel<<<PA_BLOCKS, 256, 0, stream>>>(src, dst, binCursor, ebuf);
    binsort_kernel<<<NBINS, 256, 0, stream>>>(ebuf, binBase, esrc, offs);

    // fused layers (gather + split-K GEMM in one kernel each)
    fused_layer_kernel<<<NBINS, 256, 0, stream>>>(x, x, esrc, offs, Wl1, Wr1, b1, h, 1);
    fused_layer_kernel<<<NBINS, 256, 0, stream>>>(h, h, esrc, offs, Wl2, Wr2, b2, out, 0);
}

// Round 10
// 133.415 us; speedup vs baseline: 6.0674x; 1.0320x over previous
//
#include <hip/hip_runtime.h>
#include <hip/hip_bf16.h>

#define NN 50000
#define EE 800000
#define DD 64
#define NBINS 782                  // ceil(NN / 64)
#define PA_BLOCKS 256
#define PA_CHUNK (EE / PA_BLOCKS)  // 3125

__device__ inline unsigned short f2bf(float f) {          // RNE float->bf16
    unsigned u = __float_as_uint(f);
    return (unsigned short)((u + 0x7FFF + ((u >> 16) & 1)) >> 16);
}
__device__ inline float bf2f(unsigned short u) {
    return __uint_as_float((unsigned)u << 16);
}

// ---------------- fp32 -> bf16 mirror (RNE) --------------------------------
__global__ void cvt_kernel(const float* __restrict__ in,
                           unsigned short* __restrict__ outb) {
    int i = blockIdx.x * 256 + threadIdx.x;       // i indexes float4 chunks
    if (i < NN * DD / 4) {
        float4 v = reinterpret_cast<const float4*>(in)[i];
        ushort4 u;
        u.x = f2bf(v.x); u.y = f2bf(v.y); u.z = f2bf(v.z); u.w = f2bf(v.w);
        reinterpret_cast<ushort4*>(outb)[i] = u;
    }
}

// ---------------- per-block bin histogram -> partial[block][bin] -----------
__global__ void binhist_kernel(const int* __restrict__ dst, int* __restrict__ partial) {
    __shared__ int hist[NBINS];
    const int tid = threadIdx.x;
    for (int i = tid; i < NBINS; i += 256) hist[i] = 0;
    __syncthreads();
    const int e0 = blockIdx.x * PA_CHUNK;
    for (int e = e0 + tid; e < e0 + PA_CHUNK; e += 256)
        atomicAdd(&hist[dst[e] >> 6], 1);
    __syncthreads();
    int* row = partial + (size_t)blockIdx.x * NBINS;
    for (int i = tid; i < NBINS; i += 256) row[i] = hist[i];
}

// ---------------- column-sum partials -> binCount (no atomics) -------------
__global__ void binsum_kernel(const int* __restrict__ partial, int* __restrict__ binCount) {
    int j = blockIdx.x * 256 + threadIdx.x;
    if (j < NBINS) {
        int s = 0;
        #pragma unroll 8
        for (int b = 0; b < PA_BLOCKS; ++b)
            s += partial[(size_t)b * NBINS + j];
        binCount[j] = s;
    }
}

// ---------------- exclusive scan over 782 bins (one block) -----------------
__global__ void binscan_kernel(const int* __restrict__ binCount,
                               int* __restrict__ binBase, int* __restrict__ binCursor) {
    __shared__ int s[1024];
    const int tid = threadIdx.x;
    int v = (tid < NBINS) ? binCount[tid] : 0;
    s[tid] = v;
    __syncthreads();
    #pragma unroll
    for (int o = 1; o < 1024; o <<= 1) {
        int t = (tid >= o) ? s[tid - o] : 0;
        __syncthreads();
        s[tid] += t;
        __syncthreads();
    }
    if (tid < NBINS) {
        int b = s[tid] - v;        // exclusive
        binBase[tid] = b;
        binCursor[tid] = b;
    }
    if (tid == 0) binBase[NBINS] = EE;
}

// ---------------- partition edges into bin segments ------------------------
__global__ void binscatter_kernel(const int* __restrict__ src, const int* __restrict__ dst,
                                  int* __restrict__ binCursor, unsigned* __restrict__ ebuf) {
    __shared__ int hist[NBINS];
    __shared__ int base[NBINS];
    const int tid = threadIdx.x;
    for (int i = tid; i < NBINS; i += 256) hist[i] = 0;
    __syncthreads();
    const int e0 = blockIdx.x * PA_CHUNK;
    for (int e = e0 + tid; e < e0 + PA_CHUNK; e += 256)
        atomicAdd(&hist[dst[e] >> 6], 1);
    __syncthreads();
    for (int i = tid; i < NBINS; i += 256) {
        int c = hist[i];
        base[i] = c ? atomicAdd(&binCursor[i], c) : 0;
        hist[i] = 0;               // reuse as local cursor
    }
    __syncthreads();
    for (int e = e0 + tid; e < e0 + PA_CHUNK; e += 256) {
        int d = dst[e];
        int b = d >> 6;
        int off = atomicAdd(&hist[b], 1);
        ebuf[base[b] + off] = ((unsigned)(d & 63) << 16) | (unsigned)src[e];
    }
}

// ---------------- node-sort within each bin -> esrc (ushort) + offs --------
__global__ void binsort_kernel(const unsigned* __restrict__ ebuf,
                               const int* __restrict__ binBase,
                               unsigned short* __restrict__ esrc,
                               int* __restrict__ offs) {
    __shared__ int hist[64];
    __shared__ int cur[64];
    const int tid = threadIdx.x;
    const int b = blockIdx.x;
    const int e0 = binBase[b], e1 = binBase[b + 1];
    if (tid < 64) hist[tid] = 0;
    __syncthreads();
    for (int e = e0 + tid; e < e1; e += 256)
        atomicAdd(&hist[(ebuf[e] >> 16) & 63], 1);
    __syncthreads();
    if (tid == 0) {
        int run = e0;
        #pragma unroll
        for (int i = 0; i < 64; ++i) { int c = hist[i]; cur[i] = run; run += c; }
    }
    __syncthreads();
    if (tid < 64) {
        int node = b * 64 + tid;
        if (node <= NN) offs[node] = cur[tid];   // node==NN lands exactly at EE
    }
    __syncthreads();
    for (int e = e0 + tid; e < e1; e += 256) {
        unsigned p = ebuf[e];
        int n = (p >> 16) & 63;
        int pos = atomicAdd(&cur[n], 1);
        esrc[pos] = (unsigned short)(p & 0xFFFFu);
    }
}

// ---------------- fused layer ------------------------------------------------
// pass 0: A = mean of bf16 neighbor rows (random reads, half traffic), W=Wl
// pass 1: A = fp32 self rows (coalesced, own tile only),              W=Wr
// epilogue: out fp32 (+ optional bf16 mirror for next layer's gather).
__launch_bounds__(256, 4)
__global__ void fused_layer_kernel(const unsigned short* __restrict__ gsrc,
                                   const float* __restrict__ xin,
                                   const unsigned short* __restrict__ esrc,
                                   const int* __restrict__ offs,
                                   const float* __restrict__ Wl,
                                   const float* __restrict__ Wr,
                                   const float* __restrict__ bias,
                                   float* __restrict__ outp,
                                   unsigned short* __restrict__ outbf,
                                   int relu) {
    __shared__ float A[64 * 64];    // [n][k ^ ((n&15)<<2)]
    __shared__ float W[64 * 64];    // [k][j]
    const int tid = threadIdx.x;
    const int base = blockIdx.x * 64;
    const int tc = (tid & 15) * 4;
    const int tr = (tid >> 4) * 4;

    float acc[4][4];
    float4 bv = *reinterpret_cast<const float4*>(bias + tc);
    #pragma unroll
    for (int i = 0; i < 4; ++i) {
        acc[i][0] = bv.x; acc[i][1] = bv.y; acc[i][2] = bv.z; acc[i][3] = bv.w;
    }

    // ===== pass 0: gather bf16 neighbor means, W = Wl =====
    #pragma unroll
    for (int i = 0; i < 4; ++i) {
        int idx = (i * 256 + tid) * 4;
        *reinterpret_cast<float4*>(&W[idx]) =
            *reinterpret_cast<const float4*>(Wl + idx);
    }
    const int q = (tid & 15) << 2;   // feature chunk
    const int slot = tid >> 4;       // 0..15
    #pragma unroll
    for (int rep = 0; rep < 4; ++rep) {
        int n = slot + (rep << 4);   // 0..63
        int node = base + n;
        float ax = 0.f, ay = 0.f, az = 0.f, aw = 0.f;
        if (node < NN) {
            int e0 = offs[node], e1 = offs[node + 1];
            int e = e0;
            for (; e + 3 < e1; e += 4) {
                int s0 = esrc[e], s1 = esrc[e + 1], s2 = esrc[e + 2], s3 = esrc[e + 3];
                ushort4 u0 = *reinterpret_cast<const ushort4*>(gsrc + (size_t)s0 * DD + q);
                ushort4 u1 = *reinterpret_cast<const ushort4*>(gsrc + (size_t)s1 * DD + q);
                ushort4 u2 = *reinterpret_cast<const ushort4*>(gsrc + (size_t)s2 * DD + q);
                ushort4 u3 = *reinterpret_cast<const ushort4*>(gsrc + (size_t)s3 * DD + q);
                ax += (bf2f(u0.x) + bf2f(u1.x)) + (bf2f(u2.x) + bf2f(u3.x));
                ay += (bf2f(u0.y) + bf2f(u1.y)) + (bf2f(u2.y) + bf2f(u3.y));
                az += (bf2f(u0.z) + bf2f(u1.z)) + (bf2f(u2.z) + bf2f(u3.z));
                aw += (bf2f(u0.w) + bf2f(u1.w)) + (bf2f(u2.w) + bf2f(u3.w));
            }
            for (; e < e1; ++e) {
                int s0 = esrc[e];
                ushort4 u0 = *reinterpret_cast<const ushort4*>(gsrc + (size_t)s0 * DD + q);
                ax += bf2f(u0.x); ay += bf2f(u0.y); az += bf2f(u0.z); aw += bf2f(u0.w);
            }
            float iv = (e1 > e0) ? (1.0f / (float)(e1 - e0)) : 0.0f;
            ax *= iv; ay *= iv; az *= iv; aw *= iv;
        }
        *reinterpret_cast<float4*>(&A[n * 64 + (q ^ ((n & 15) << 2))]) =
            make_float4(ax, ay, az, aw);
    }
    __syncthreads();

    #pragma unroll 4
    for (int k = 0; k < 64; k += 4) {
        float av[4][4];
        #pragma unroll
        for (int i = 0; i < 4; ++i) {
            int row = tr + i;
            float4 a = *reinterpret_cast<const float4*>(
                &A[row * 64 + (k ^ ((row & 15) << 2))]);
            av[i][0] = a.x; av[i][1] = a.y; av[i][2] = a.z; av[i][3] = a.w;
        }
        #pragma unroll
        for (int kk = 0; kk < 4; ++kk) {
            float4 w = *reinterpret_cast<const float4*>(&W[(k + kk) * 64 + tc]);
            #pragma unroll
            for (int i = 0; i < 4; ++i) {
                acc[i][0] += av[i][kk] * w.x;
                acc[i][1] += av[i][kk] * w.y;
                acc[i][2] += av[i][kk] * w.z;
                acc[i][3] += av[i][kk] * w.w;
            }
        }
    }
    __syncthreads();     // done reading A/W; safe to restage

    // ===== pass 1: A = fp32 self rows (coalesced, own tile), W = Wr =====
    #pragma unroll
    for (int i = 0; i < 4; ++i) {
        int idx = (i * 256 + tid) * 4;
        *reinterpret_cast<float4*>(&W[idx]) =
            *reinterpret_cast<const float4*>(Wr + idx);
    }
    #pragma unroll
    for (int i = 0; i < 4; ++i) {
        int t2 = i * 256 + tid;
        int n  = t2 >> 4;
        int c4 = (t2 & 15) << 2;
        int node = base + n;
        float4 v = make_float4(0.f, 0.f, 0.f, 0.f);
        if (node < NN)
            v = *reinterpret_cast<const float4*>(xin + (size_t)node * DD + c4);
        *reinterpret_cast<float4*>(&A[n * 64 + (c4 ^ ((n & 15) << 2))]) = v;
    }
    __syncthreads();

    #pragma unroll 4
    for (int k = 0; k < 64; k += 4) {
        float av[4][4];
        #pragma unroll
        for (int i = 0; i < 4; ++i) {
            int row = tr + i;
            float4 a = *reinterpret_cast<const float4*>(
                &A[row * 64 + (k ^ ((row & 15) << 2))]);
            av[i][0] = a.x; av[i][1] = a.y; av[i][2] = a.z; av[i][3] = a.w;
        }
        #pragma unroll
        for (int kk = 0; kk < 4; ++kk) {
            float4 w = *reinterpret_cast<const float4*>(&W[(k + kk) * 64 + tc]);
            #pragma unroll
            for (int i = 0; i < 4; ++i) {
                acc[i][0] += av[i][kk] * w.x;
                acc[i][1] += av[i][kk] * w.y;
                acc[i][2] += av[i][kk] * w.z;
                acc[i][3] += av[i][kk] * w.w;
            }
        }
    }

    #pragma unroll
    for (int i = 0; i < 4; ++i) {
        int node = base + tr + i;
        if (node < NN) {
            float4 r = make_float4(acc[i][0], acc[i][1], acc[i][2], acc[i][3]);
            if (relu) {
                r.x = fmaxf(r.x, 0.f); r.y = fmaxf(r.y, 0.f);
                r.z = fmaxf(r.z, 0.f); r.w = fmaxf(r.w, 0.f);
            }
            *reinterpret_cast<float4*>(outp + (size_t)node * DD + tc) = r;
            if (outbf) {
                ushort4 u;
                u.x = f2bf(r.x); u.y = f2bf(r.y); u.z = f2bf(r.z); u.w = f2bf(r.w);
                *reinterpret_cast<ushort4*>(outbf + (size_t)node * DD + tc) = u;
            }
        }
    }
}

static inline size_t rup(size_t b) { return (b + 255) & ~(size_t)255; }

extern "C" void kernel_launch(void* const* d_in, const int* in_sizes, int n_in,
                              void* d_out, int out_size, void* d_ws, size_t ws_size,
                              hipStream_t stream) {
    const float* x   = (const float*)d_in[0];
    const int*   ei  = (const int*)d_in[1];
    const float* Wl1 = (const float*)d_in[2];
    const float* Wr1 = (const float*)d_in[3];
    const float* b1  = (const float*)d_in[4];
    const float* Wl2 = (const float*)d_in[5];
    const float* Wr2 = (const float*)d_in[6];
    const float* b2  = (const float*)d_in[7];
    float* out = (float*)d_out;

    const int* src = ei;        // edge_index[0]
    const int* dst = ei + EE;   // edge_index[1]

    // workspace layout (256B-aligned regions), ~18.6 MB
    char* p = (char*)d_ws;
    int* partial         = (int*)p;            p += rup((size_t)PA_BLOCKS * NBINS * 4);
    int* binCount        = (int*)p;            p += rup((size_t)NBINS * 4);
    int* binBase         = (int*)p;            p += rup((size_t)(NBINS + 1) * 4);
    int* binCursor       = (int*)p;            p += rup((size_t)NBINS * 4);
    unsigned* ebuf       = (unsigned*)p;       p += rup((size_t)EE * 4);
    unsigned short* esrc = (unsigned short*)p; p += rup((size_t)EE * 2);
    int* offs            = (int*)p;            p += rup((size_t)(NN + 1) * 4);
    unsigned short* xbf  = (unsigned short*)p; p += rup((size_t)NN * DD * 2);
    unsigned short* hbf  = (unsigned short*)p; p += rup((size_t)NN * DD * 2);
    float* h             = out;   // fp32 h in d_out: cross-tile gather reads
                                  // come from hbf; fp32 h is read own-tile only.

    // two-level CSR build (no memset anywhere) + bf16 mirror of x
    binhist_kernel<<<PA_BLOCKS, 256, 0, stream>>>(dst, partial);
    binsum_kernel<<<(NBINS + 255) / 256, 256, 0, stream>>>(partial, binCount);
    binscan_kernel<<<1, 1024, 0, stream>>>(binCount, binBase, binCursor);
    binscatter_kernel<<<PA_BLOCKS, 256, 0, stream>>>(src, dst, binCursor, ebuf);
    binsort_kernel<<<NBINS, 256, 0, stream>>>(ebuf, binBase, esrc, offs);
    cvt_kernel<<<(NN * DD / 4 + 255) / 256, 256, 0, stream>>>(x, xbf);

    // fused layers
    fused_layer_kernel<<<NBINS, 256, 0, stream>>>(xbf, x, esrc, offs,
                                                  Wl1, Wr1, b1, h, hbf, 1);
    fused_layer_kernel<<<NBINS, 256, 0, stream>>>(hbf, h, esrc, offs,
                                                  Wl2, Wr2, b2, out, nullptr, 0);
}

// Round 11
// 124.154 us; speedup vs baseline: 6.5200x; 1.0746x over previous
//
#include <hip/hip_runtime.h>
#include <hip/hip_bf16.h>

#define NN 50000
#define EE 800000
#define DD 64
#define NBINS 782                  // ceil(NN / 64)
#define PA_BLOCKS 256
#define PA_CHUNK (EE / PA_BLOCKS)  // 3125

__device__ inline unsigned short f2bf(float f) {          // RNE float->bf16
    unsigned u = __float_as_uint(f);
    return (unsigned short)((u + 0x7FFF + ((u >> 16) & 1)) >> 16);
}
__device__ inline float bf2f(unsigned short u) {
    return __uint_as_float((unsigned)u << 16);
}

// ---------------- fp32 -> bf16 mirror (RNE) --------------------------------
__global__ void cvt_kernel(const float* __restrict__ in,
                           unsigned short* __restrict__ outb) {
    int i = blockIdx.x * 256 + threadIdx.x;       // i indexes float4 chunks
    if (i < NN * DD / 4) {
        float4 v = reinterpret_cast<const float4*>(in)[i];
        ushort4 u;
        u.x = f2bf(v.x); u.y = f2bf(v.y); u.z = f2bf(v.z); u.w = f2bf(v.w);
        reinterpret_cast<ushort4*>(outb)[i] = u;
    }
}

// ---------------- per-block bin histogram -> partial[block][bin] -----------
__global__ void binhist_kernel(const int* __restrict__ dst, int* __restrict__ partial) {
    __shared__ int hist[NBINS];
    const int tid = threadIdx.x;
    for (int i = tid; i < NBINS; i += 256) hist[i] = 0;
    __syncthreads();
    const int e0 = blockIdx.x * PA_CHUNK;
    for (int e = e0 + tid; e < e0 + PA_CHUNK; e += 256)
        atomicAdd(&hist[dst[e] >> 6], 1);
    __syncthreads();
    int* row = partial + (size_t)blockIdx.x * NBINS;
    for (int i = tid; i < NBINS; i += 256) row[i] = hist[i];
}

// ---------------- column-sum partials -> binCount (no atomics) -------------
__global__ void binsum_kernel(const int* __restrict__ partial, int* __restrict__ binCount) {
    int j = blockIdx.x * 256 + threadIdx.x;
    if (j < NBINS) {
        int s = 0;
        #pragma unroll 8
        for (int b = 0; b < PA_BLOCKS; ++b)
            s += partial[(size_t)b * NBINS + j];
        binCount[j] = s;
    }
}

// ---------------- exclusive scan over 782 bins (one block) -----------------
__global__ void binscan_kernel(const int* __restrict__ binCount,
                               int* __restrict__ binBase, int* __restrict__ binCursor) {
    __shared__ int s[1024];
    const int tid = threadIdx.x;
    int v = (tid < NBINS) ? binCount[tid] : 0;
    s[tid] = v;
    __syncthreads();
    #pragma unroll
    for (int o = 1; o < 1024; o <<= 1) {
        int t = (tid >= o) ? s[tid - o] : 0;
        __syncthreads();
        s[tid] += t;
        __syncthreads();
    }
    if (tid < NBINS) {
        int b = s[tid] - v;        // exclusive
        binBase[tid] = b;
        binCursor[tid] = b;
    }
    if (tid == 0) binBase[NBINS] = EE;
}

// ---------------- partition edges into bin segments ------------------------
__global__ void binscatter_kernel(const int* __restrict__ src, const int* __restrict__ dst,
                                  int* __restrict__ binCursor, unsigned* __restrict__ ebuf) {
    __shared__ int hist[NBINS];
    __shared__ int base[NBINS];
    const int tid = threadIdx.x;
    for (int i = tid; i < NBINS; i += 256) hist[i] = 0;
    __syncthreads();
    const int e0 = blockIdx.x * PA_CHUNK;
    for (int e = e0 + tid; e < e0 + PA_CHUNK; e += 256)
        atomicAdd(&hist[dst[e] >> 6], 1);
    __syncthreads();
    for (int i = tid; i < NBINS; i += 256) {
        int c = hist[i];
        base[i] = c ? atomicAdd(&binCursor[i], c) : 0;
        hist[i] = 0;               // reuse as local cursor
    }
    __syncthreads();
    for (int e = e0 + tid; e < e0 + PA_CHUNK; e += 256) {
        int d = dst[e];
        int b = d >> 6;
        int off = atomicAdd(&hist[b], 1);
        ebuf[base[b] + off] = ((unsigned)(d & 63) << 16) | (unsigned)src[e];
    }
}

// ---------------- node-sort within each bin -> esrc (ushort) + offs --------
__global__ void binsort_kernel(const unsigned* __restrict__ ebuf,
                               const int* __restrict__ binBase,
                               unsigned short* __restrict__ esrc,
                               int* __restrict__ offs) {
    __shared__ int hist[64];
    __shared__ int cur[64];
    const int tid = threadIdx.x;
    const int b = blockIdx.x;
    const int e0 = binBase[b], e1 = binBase[b + 1];
    if (tid < 64) hist[tid] = 0;
    __syncthreads();
    for (int e = e0 + tid; e < e1; e += 256)
        atomicAdd(&hist[(ebuf[e] >> 16) & 63], 1);
    __syncthreads();
    if (tid == 0) {
        int run = e0;
        #pragma unroll
        for (int i = 0; i < 64; ++i) { int c = hist[i]; cur[i] = run; run += c; }
    }
    __syncthreads();
    if (tid < 64) {
        int node = b * 64 + tid;
        if (node <= NN) offs[node] = cur[tid];   // node==NN lands exactly at EE
    }
    __syncthreads();
    for (int e = e0 + tid; e < e1; e += 256) {
        unsigned p = ebuf[e];
        int n = (p >> 16) & 63;
        int pos = atomicAdd(&cur[n], 1);
        esrc[pos] = (unsigned short)(p & 0xFFFFu);
    }
}

// ---------------- gather-aggregate (bf16 in, bf16 out) ---------------------
// Register-only, 3125 blocks, 16 lanes/node (ushort4 = 8B each), 8-deep
// unroll: high occupancy + ILP for the latency-bound random row reads.
__global__ void gather_kernel(const unsigned short* __restrict__ feat,
                              const unsigned short* __restrict__ esrc,
                              const int* __restrict__ offs,
                              unsigned short* __restrict__ aggbf) {
    int n = blockIdx.x * 16 + (threadIdx.x >> 4);
    if (n >= NN) return;
    int q = (threadIdx.x & 15) << 2;
    int e0 = offs[n], e1 = offs[n + 1];
    float ax = 0.f, ay = 0.f, az = 0.f, aw = 0.f;
    int e = e0;
    for (; e + 7 < e1; e += 8) {
        ushort4 u0 = *reinterpret_cast<const ushort4*>(feat + (size_t)esrc[e + 0] * DD + q);
        ushort4 u1 = *reinterpret_cast<const ushort4*>(feat + (size_t)esrc[e + 1] * DD + q);
        ushort4 u2 = *reinterpret_cast<const ushort4*>(feat + (size_t)esrc[e + 2] * DD + q);
        ushort4 u3 = *reinterpret_cast<const ushort4*>(feat + (size_t)esrc[e + 3] * DD + q);
        ushort4 u4 = *reinterpret_cast<const ushort4*>(feat + (size_t)esrc[e + 4] * DD + q);
        ushort4 u5 = *reinterpret_cast<const ushort4*>(feat + (size_t)esrc[e + 5] * DD + q);
        ushort4 u6 = *reinterpret_cast<const ushort4*>(feat + (size_t)esrc[e + 6] * DD + q);
        ushort4 u7 = *reinterpret_cast<const ushort4*>(feat + (size_t)esrc[e + 7] * DD + q);
        ax += ((bf2f(u0.x) + bf2f(u1.x)) + (bf2f(u2.x) + bf2f(u3.x)))
            + ((bf2f(u4.x) + bf2f(u5.x)) + (bf2f(u6.x) + bf2f(u7.x)));
        ay += ((bf2f(u0.y) + bf2f(u1.y)) + (bf2f(u2.y) + bf2f(u3.y)))
            + ((bf2f(u4.y) + bf2f(u5.y)) + (bf2f(u6.y) + bf2f(u7.y)));
        az += ((bf2f(u0.z) + bf2f(u1.z)) + (bf2f(u2.z) + bf2f(u3.z)))
            + ((bf2f(u4.z) + bf2f(u5.z)) + (bf2f(u6.z) + bf2f(u7.z)));
        aw += ((bf2f(u0.w) + bf2f(u1.w)) + (bf2f(u2.w) + bf2f(u3.w)))
            + ((bf2f(u4.w) + bf2f(u5.w)) + (bf2f(u6.w) + bf2f(u7.w)));
    }
    for (; e + 3 < e1; e += 4) {
        ushort4 u0 = *reinterpret_cast<const ushort4*>(feat + (size_t)esrc[e + 0] * DD + q);
        ushort4 u1 = *reinterpret_cast<const ushort4*>(feat + (size_t)esrc[e + 1] * DD + q);
        ushort4 u2 = *reinterpret_cast<const ushort4*>(feat + (size_t)esrc[e + 2] * DD + q);
        ushort4 u3 = *reinterpret_cast<const ushort4*>(feat + (size_t)esrc[e + 3] * DD + q);
        ax += (bf2f(u0.x) + bf2f(u1.x)) + (bf2f(u2.x) + bf2f(u3.x));
        ay += (bf2f(u0.y) + bf2f(u1.y)) + (bf2f(u2.y) + bf2f(u3.y));
        az += (bf2f(u0.z) + bf2f(u1.z)) + (bf2f(u2.z) + bf2f(u3.z));
        aw += (bf2f(u0.w) + bf2f(u1.w)) + (bf2f(u2.w) + bf2f(u3.w));
    }
    for (; e < e1; ++e) {
        ushort4 u0 = *reinterpret_cast<const ushort4*>(feat + (size_t)esrc[e] * DD + q);
        ax += bf2f(u0.x); ay += bf2f(u0.y); az += bf2f(u0.z); aw += bf2f(u0.w);
    }
    float iv = (e1 > e0) ? (1.0f / (float)(e1 - e0)) : 0.0f;
    ushort4 r;
    r.x = f2bf(ax * iv); r.y = f2bf(ay * iv); r.z = f2bf(az * iv); r.w = f2bf(aw * iv);
    *reinterpret_cast<ushort4*>(aggbf + (size_t)n * DD + q) = r;
}

// ---------------- SAGE layer GEMM, split-K two-pass ------------------------
// pass 0: A = bf16 agg tile, W = Wl ; pass 1: A = fp32 self rows, W = Wr.
// 32KB LDS; epilogue writes fp32 out (+ optional bf16 mirror).
__launch_bounds__(256, 4)
__global__ void layer_kernel(const unsigned short* __restrict__ aggbf,
                             const float* __restrict__ xin,
                             const float* __restrict__ Wl,
                             const float* __restrict__ Wr,
                             const float* __restrict__ bias,
                             float* __restrict__ outp,
                             unsigned short* __restrict__ outbf,
                             int relu) {
    __shared__ float A[64 * 64];    // [n][k ^ ((n&15)<<2)]
    __shared__ float W[64 * 64];    // [k][j]
    const int tid = threadIdx.x;
    const int base = blockIdx.x * 64;
    const int tc = (tid & 15) * 4;
    const int tr = (tid >> 4) * 4;

    float acc[4][4];
    float4 bv = *reinterpret_cast<const float4*>(bias + tc);
    #pragma unroll
    for (int i = 0; i < 4; ++i) {
        acc[i][0] = bv.x; acc[i][1] = bv.y; acc[i][2] = bv.z; acc[i][3] = bv.w;
    }

    for (int pass = 0; pass < 2; ++pass) {
        if (pass) __syncthreads();          // reads of previous tiles done
        const float* Wsrc = pass ? Wr : Wl;

        // stage W (64x64 row-major, contiguous)
        #pragma unroll
        for (int i = 0; i < 4; ++i) {
            int idx = (i * 256 + tid) * 4;
            *reinterpret_cast<float4*>(&W[idx]) =
                *reinterpret_cast<const float4*>(Wsrc + idx);
        }
        // stage A tile
        #pragma unroll
        for (int i = 0; i < 4; ++i) {
            int t2 = i * 256 + tid;
            int n  = t2 >> 4;
            int c4 = (t2 & 15) << 2;
            int node = base + n;
            float4 v = make_float4(0.f, 0.f, 0.f, 0.f);
            if (node < NN) {
                if (pass == 0) {
                    ushort4 u = *reinterpret_cast<const ushort4*>(
                        aggbf + (size_t)node * DD + c4);
                    v = make_float4(bf2f(u.x), bf2f(u.y), bf2f(u.z), bf2f(u.w));
                } else {
                    v = *reinterpret_cast<const float4*>(xin + (size_t)node * DD + c4);
                }
            }
            *reinterpret_cast<float4*>(&A[n * 64 + (c4 ^ ((n & 15) << 2))]) = v;
        }
        __syncthreads();

        #pragma unroll 4
        for (int k = 0; k < 64; k += 4) {
            float av[4][4];
            #pragma unroll
            for (int i = 0; i < 4; ++i) {
                int row = tr + i;
                float4 a = *reinterpret_cast<const float4*>(
                    &A[row * 64 + (k ^ ((row & 15) << 2))]);
                av[i][0] = a.x; av[i][1] = a.y; av[i][2] = a.z; av[i][3] = a.w;
            }
            #pragma unroll
            for (int kk = 0; kk < 4; ++kk) {
                float4 w = *reinterpret_cast<const float4*>(&W[(k + kk) * 64 + tc]);
                #pragma unroll
                for (int i = 0; i < 4; ++i) {
                    acc[i][0] += av[i][kk] * w.x;
                    acc[i][1] += av[i][kk] * w.y;
                    acc[i][2] += av[i][kk] * w.z;
                    acc[i][3] += av[i][kk] * w.w;
                }
            }
        }
    }

    #pragma unroll
    for (int i = 0; i < 4; ++i) {
        int node = base + tr + i;
        if (node < NN) {
            float4 r = make_float4(acc[i][0], acc[i][1], acc[i][2], acc[i][3]);
            if (relu) {
                r.x = fmaxf(r.x, 0.f); r.y = fmaxf(r.y, 0.f);
                r.z = fmaxf(r.z, 0.f); r.w = fmaxf(r.w, 0.f);
            }
            *reinterpret_cast<float4*>(outp + (size_t)node * DD + tc) = r;
            if (outbf) {
                ushort4 u;
                u.x = f2bf(r.x); u.y = f2bf(r.y); u.z = f2bf(r.z); u.w = f2bf(r.w);
                *reinterpret_cast<ushort4*>(outbf + (size_t)node * DD + tc) = u;
            }
        }
    }
}

static inline size_t rup(size_t b) { return (b + 255) & ~(size_t)255; }

extern "C" void kernel_launch(void* const* d_in, const int* in_sizes, int n_in,
                              void* d_out, int out_size, void* d_ws, size_t ws_size,
                              hipStream_t stream) {
    const float* x   = (const float*)d_in[0];
    const int*   ei  = (const int*)d_in[1];
    const float* Wl1 = (const float*)d_in[2];
    const float* Wr1 = (const float*)d_in[3];
    const float* b1  = (const float*)d_in[4];
    const float* Wl2 = (const float*)d_in[5];
    const float* Wr2 = (const float*)d_in[6];
    const float* b2  = (const float*)d_in[7];
    float* out = (float*)d_out;

    const int* src = ei;        // edge_index[0]
    const int* dst = ei + EE;   // edge_index[1]

    // workspace layout (256B-aligned regions), ~25 MB
    char* p = (char*)d_ws;
    int* partial          = (int*)p;            p += rup((size_t)PA_BLOCKS * NBINS * 4);
    int* binCount         = (int*)p;            p += rup((size_t)NBINS * 4);
    int* binBase          = (int*)p;            p += rup((size_t)(NBINS + 1) * 4);
    int* binCursor        = (int*)p;            p += rup((size_t)NBINS * 4);
    unsigned* ebuf        = (unsigned*)p;       p += rup((size_t)EE * 4);
    unsigned short* esrc  = (unsigned short*)p; p += rup((size_t)EE * 2);
    int* offs             = (int*)p;            p += rup((size_t)(NN + 1) * 4);
    unsigned short* xbf   = (unsigned short*)p; p += rup((size_t)NN * DD * 2);
    unsigned short* hbf   = (unsigned short*)p; p += rup((size_t)NN * DD * 2);
    unsigned short* aggbf = (unsigned short*)p; p += rup((size_t)NN * DD * 2);
    float* h              = out;  // fp32 h in d_out: cross-tile gather reads
                                  // come from hbf; fp32 h is read own-tile only.

    // two-level CSR build (no memset anywhere) + bf16 mirror of x
    binhist_kernel<<<PA_BLOCKS, 256, 0, stream>>>(dst, partial);
    binsum_kernel<<<(NBINS + 255) / 256, 256, 0, stream>>>(partial, binCount);
    binscan_kernel<<<1, 1024, 0, stream>>>(binCount, binBase, binCursor);
    binscatter_kernel<<<PA_BLOCKS, 256, 0, stream>>>(src, dst, binCursor, ebuf);
    binsort_kernel<<<NBINS, 256, 0, stream>>>(ebuf, binBase, esrc, offs);
    cvt_kernel<<<(NN * DD / 4 + 255) / 256, 256, 0, stream>>>(x, xbf);

    // layer 1: high-occupancy gather, then split-K GEMM
    gather_kernel<<<NN / 16, 256, 0, stream>>>(xbf, esrc, offs, aggbf);
    layer_kernel<<<NBINS, 256, 0, stream>>>(aggbf, x, Wl1, Wr1, b1, h, hbf, 1);

    // layer 2
    gather_kernel<<<NN / 16, 256, 0, stream>>>(hbf, esrc, offs, aggbf);
    layer_kernel<<<NBINS, 256, 0, stream>>>(aggbf, h, Wl2, Wr2, b2, out, nullptr, 0);
}

// Round 12
// 116.998 us; speedup vs baseline: 6.9188x; 1.0612x over previous
//
#include <hip/hip_runtime.h>
#include <hip/hip_bf16.h>

#define NN 50000
#define EE 800000
#define DD 64
#define NBINS 782                  // ceil(NN / 64)
#define PA_BLOCKS 256
#define PA_CHUNK (EE / PA_BLOCKS)  // 3125
#define NLB 1563                   // ceil(NN / 32)

__device__ inline unsigned short f2bf(float f) {          // RNE float->bf16
    unsigned u = __float_as_uint(f);
    return (unsigned short)((u + 0x7FFF + ((u >> 16) & 1)) >> 16);
}
__device__ inline float bflo(unsigned u) { return __uint_as_float(u << 16); }
__device__ inline float bfhi(unsigned u) { return __uint_as_float(u & 0xFFFF0000u); }
__device__ inline unsigned bfpack(float a, float b) {     // [lo=a, hi=b]
    return (unsigned)f2bf(a) | ((unsigned)f2bf(b) << 16);
}

// ---------------- fp32 -> bf16 mirror (RNE) --------------------------------
__global__ void cvt_kernel(const float* __restrict__ in,
                           unsigned short* __restrict__ outb) {
    int i = blockIdx.x * 256 + threadIdx.x;       // i indexes float4 chunks
    if (i < NN * DD / 4) {
        float4 v = reinterpret_cast<const float4*>(in)[i];
        ushort4 u;
        u.x = f2bf(v.x); u.y = f2bf(v.y); u.z = f2bf(v.z); u.w = f2bf(v.w);
        reinterpret_cast<ushort4*>(outb)[i] = u;
    }
}

// ---------------- per-block bin histogram -> partial[block][bin] -----------
__global__ void binhist_kernel(const int* __restrict__ dst, int* __restrict__ partial) {
    __shared__ int hist[NBINS];
    const int tid = threadIdx.x;
    for (int i = tid; i < NBINS; i += 256) hist[i] = 0;
    __syncthreads();
    const int e0 = blockIdx.x * PA_CHUNK;
    for (int e = e0 + tid; e < e0 + PA_CHUNK; e += 256)
        atomicAdd(&hist[dst[e] >> 6], 1);
    __syncthreads();
    int* row = partial + (size_t)blockIdx.x * NBINS;
    for (int i = tid; i < NBINS; i += 256) row[i] = hist[i];
}

// ---------------- column-sum partials -> binCount (no atomics) -------------
__global__ void binsum_kernel(const int* __restrict__ partial, int* __restrict__ binCount) {
    int j = blockIdx.x * 256 + threadIdx.x;
    if (j < NBINS) {
        int s = 0;
        #pragma unroll 8
        for (int b = 0; b < PA_BLOCKS; ++b)
            s += partial[(size_t)b * NBINS + j];
        binCount[j] = s;
    }
}

// ---------------- exclusive scan over 782 bins (one block) -----------------
__global__ void binscan_kernel(const int* __restrict__ binCount,
                               int* __restrict__ binBase, int* __restrict__ binCursor) {
    __shared__ int s[1024];
    const int tid = threadIdx.x;
    int v = (tid < NBINS) ? binCount[tid] : 0;
    s[tid] = v;
    __syncthreads();
    #pragma unroll
    for (int o = 1; o < 1024; o <<= 1) {
        int t = (tid >= o) ? s[tid - o] : 0;
        __syncthreads();
        s[tid] += t;
        __syncthreads();
    }
    if (tid < NBINS) {
        int b = s[tid] - v;        // exclusive
        binBase[tid] = b;
        binCursor[tid] = b;
    }
    if (tid == 0) binBase[NBINS] = EE;
}

// ---------------- partition edges into bin segments ------------------------
__global__ void binscatter_kernel(const int* __restrict__ src, const int* __restrict__ dst,
                                  int* __restrict__ binCursor, unsigned* __restrict__ ebuf) {
    __shared__ int hist[NBINS];
    __shared__ int base[NBINS];
    const int tid = threadIdx.x;
    for (int i = tid; i < NBINS; i += 256) hist[i] = 0;
    __syncthreads();
    const int e0 = blockIdx.x * PA_CHUNK;
    for (int e = e0 + tid; e < e0 + PA_CHUNK; e += 256)
        atomicAdd(&hist[dst[e] >> 6], 1);
    __syncthreads();
    for (int i = tid; i < NBINS; i += 256) {
        int c = hist[i];
        base[i] = c ? atomicAdd(&binCursor[i], c) : 0;
        hist[i] = 0;               // reuse as local cursor
    }
    __syncthreads();
    for (int e = e0 + tid; e < e0 + PA_CHUNK; e += 256) {
        int d = dst[e];
        int b = d >> 6;
        int off = atomicAdd(&hist[b], 1);
        ebuf[base[b] + off] = ((unsigned)(d & 63) << 16) | (unsigned)src[e];
    }
}

// ---------------- node-sort within each bin -> esrc (ushort) + offs --------
__global__ void binsort_kernel(const unsigned* __restrict__ ebuf,
                               const int* __restrict__ binBase,
                               unsigned short* __restrict__ esrc,
                               int* __restrict__ offs) {
    __shared__ int hist[64];
    __shared__ int cur[64];
    const int tid = threadIdx.x;
    const int b = blockIdx.x;
    const int e0 = binBase[b], e1 = binBase[b + 1];
    if (tid < 64) hist[tid] = 0;
    __syncthreads();
    for (int e = e0 + tid; e < e1; e += 256)
        atomicAdd(&hist[(ebuf[e] >> 16) & 63], 1);
    __syncthreads();
    if (tid == 0) {
        int run = e0;
        #pragma unroll
        for (int i = 0; i < 64; ++i) { int c = hist[i]; cur[i] = run; run += c; }
    }
    __syncthreads();
    if (tid < 64) {
        int node = b * 64 + tid;
        if (node <= NN) offs[node] = cur[tid];   // node==NN lands exactly at EE
    }
    __syncthreads();
    for (int e = e0 + tid; e < e1; e += 256) {
        unsigned p = ebuf[e];
        int n = (p >> 16) & 63;
        int pos = atomicAdd(&cur[n], 1);
        esrc[pos] = (unsigned short)(p & 0xFFFFu);
    }
}

// ---------------- gather-aggregate (bf16 in, bf16 out) ---------------------
// 8 lanes/node x uint4 (16B = 8 bf16): half the VMEM instructions of 16x8B.
// 32 nodes/block, 1563 blocks, register-only, 4-edge unroll.
__global__ void gather_kernel(const unsigned short* __restrict__ feat,
                              const unsigned short* __restrict__ esrc,
                              const int* __restrict__ offs,
                              unsigned short* __restrict__ aggbf) {
    int n = blockIdx.x * 32 + (threadIdx.x >> 3);
    if (n >= NN) return;
    int q = (threadIdx.x & 7) << 3;       // bf16 elem offset: 0,8,...,56
    int e0 = offs[n], e1 = offs[n + 1];
    float a0 = 0.f, a1 = 0.f, a2 = 0.f, a3 = 0.f;
    float a4 = 0.f, a5 = 0.f, a6 = 0.f, a7 = 0.f;
    int e = e0;
    for (; e + 3 < e1; e += 4) {
        uint4 u0 = *reinterpret_cast<const uint4*>(feat + (size_t)esrc[e + 0] * DD + q);
        uint4 u1 = *reinterpret_cast<const uint4*>(feat + (size_t)esrc[e + 1] * DD + q);
        uint4 u2 = *reinterpret_cast<const uint4*>(feat + (size_t)esrc[e + 2] * DD + q);
        uint4 u3 = *reinterpret_cast<const uint4*>(feat + (size_t)esrc[e + 3] * DD + q);
        a0 += (bflo(u0.x) + bflo(u1.x)) + (bflo(u2.x) + bflo(u3.x));
        a1 += (bfhi(u0.x) + bfhi(u1.x)) + (bfhi(u2.x) + bfhi(u3.x));
        a2 += (bflo(u0.y) + bflo(u1.y)) + (bflo(u2.y) + bflo(u3.y));
        a3 += (bfhi(u0.y) + bfhi(u1.y)) + (bfhi(u2.y) + bfhi(u3.y));
        a4 += (bflo(u0.z) + bflo(u1.z)) + (bflo(u2.z) + bflo(u3.z));
        a5 += (bfhi(u0.z) + bfhi(u1.z)) + (bfhi(u2.z) + bfhi(u3.z));
        a6 += (bflo(u0.w) + bflo(u1.w)) + (bflo(u2.w) + bflo(u3.w));
        a7 += (bfhi(u0.w) + bfhi(u1.w)) + (bfhi(u2.w) + bfhi(u3.w));
    }
    for (; e < e1; ++e) {
        uint4 u0 = *reinterpret_cast<const uint4*>(feat + (size_t)esrc[e] * DD + q);
        a0 += bflo(u0.x); a1 += bfhi(u0.x);
        a2 += bflo(u0.y); a3 += bfhi(u0.y);
        a4 += bflo(u0.z); a5 += bfhi(u0.z);
        a6 += bflo(u0.w); a7 += bfhi(u0.w);
    }
    float iv = (e1 > e0) ? (1.0f / (float)(e1 - e0)) : 0.0f;
    uint4 r;
    r.x = bfpack(a0 * iv, a1 * iv);
    r.y = bfpack(a2 * iv, a3 * iv);
    r.z = bfpack(a4 * iv, a5 * iv);
    r.w = bfpack(a6 * iv, a7 * iv);
    *reinterpret_cast<uint4*>(aggbf + (size_t)n * DD + q) = r;
}

// ---------------- SAGE layer GEMM, split-K two-pass, 32-node tiles ---------
// pass 0: A = bf16 agg tile, W = Wl ; pass 1: A = bf16 self tile, W = Wr.
// 24KB LDS (8KB A + 16KB W), 1563 blocks; epilogue fp32 and/or bf16 out.
__launch_bounds__(256, 6)
__global__ void layer_kernel(const unsigned short* __restrict__ aggbf,
                             const unsigned short* __restrict__ selfbf,
                             const float* __restrict__ Wl,
                             const float* __restrict__ Wr,
                             const float* __restrict__ bias,
                             float* __restrict__ outp,
                             unsigned short* __restrict__ outbf,
                             int relu) {
    __shared__ float A[32 * 64];    // [n][k ^ ((n&15)<<2)]
    __shared__ float W[64 * 64];    // [k][j]
    const int tid = threadIdx.x;
    const int base = blockIdx.x * 32;
    const int tc = (tid & 15) * 4;  // col base
    const int tr = (tid >> 4) * 2;  // node base (2 nodes/thread)

    float acc[2][4];
    float4 bv = *reinterpret_cast<const float4*>(bias + tc);
    #pragma unroll
    for (int i = 0; i < 2; ++i) {
        acc[i][0] = bv.x; acc[i][1] = bv.y; acc[i][2] = bv.z; acc[i][3] = bv.w;
    }

    for (int pass = 0; pass < 2; ++pass) {
        if (pass) __syncthreads();          // reads of previous tiles done
        const float* Wsrc = pass ? Wr : Wl;
        const unsigned short* Asrc = pass ? selfbf : aggbf;

        // stage W (64x64 fp32 row-major, contiguous)
        #pragma unroll
        for (int i = 0; i < 4; ++i) {
            int idx = (i * 256 + tid) * 4;
            *reinterpret_cast<float4*>(&W[idx]) =
                *reinterpret_cast<const float4*>(Wsrc + idx);
        }
        // stage A tile: 32 nodes x 64 bf16; each thread one uint4 (8 bf16)
        {
            int n  = tid >> 3;              // 0..31
            int c8 = (tid & 7) << 3;        // 0,8,...,56
            int node = base + n;
            uint4 u = make_uint4(0u, 0u, 0u, 0u);
            if (node < NN)
                u = *reinterpret_cast<const uint4*>(Asrc + (size_t)node * DD + c8);
            float4 f0 = make_float4(bflo(u.x), bfhi(u.x), bflo(u.y), bfhi(u.y));
            float4 f1 = make_float4(bflo(u.z), bfhi(u.z), bflo(u.w), bfhi(u.w));
            int sw = (n & 15) << 2;
            *reinterpret_cast<float4*>(&A[n * 64 + (c8 ^ sw)]) = f0;
            *reinterpret_cast<float4*>(&A[n * 64 + ((c8 + 4) ^ sw)]) = f1;
        }
        __syncthreads();

        #pragma unroll 4
        for (int k = 0; k < 64; k += 4) {
            float av[2][4];
            #pragma unroll
            for (int i = 0; i < 2; ++i) {
                int row = tr + i;
                float4 a = *reinterpret_cast<const float4*>(
                    &A[row * 64 + (k ^ ((row & 15) << 2))]);
                av[i][0] = a.x; av[i][1] = a.y; av[i][2] = a.z; av[i][3] = a.w;
            }
            #pragma unroll
            for (int kk = 0; kk < 4; ++kk) {
                float4 w = *reinterpret_cast<const float4*>(&W[(k + kk) * 64 + tc]);
                #pragma unroll
                for (int i = 0; i < 2; ++i) {
                    acc[i][0] += av[i][kk] * w.x;
                    acc[i][1] += av[i][kk] * w.y;
                    acc[i][2] += av[i][kk] * w.z;
                    acc[i][3] += av[i][kk] * w.w;
                }
            }
        }
    }

    #pragma unroll
    for (int i = 0; i < 2; ++i) {
        int node = base + tr + i;
        if (node < NN) {
            float4 r = make_float4(acc[i][0], acc[i][1], acc[i][2], acc[i][3]);
            if (relu) {
                r.x = fmaxf(r.x, 0.f); r.y = fmaxf(r.y, 0.f);
                r.z = fmaxf(r.z, 0.f); r.w = fmaxf(r.w, 0.f);
            }
            if (outp)
                *reinterpret_cast<float4*>(outp + (size_t)node * DD + tc) = r;
            if (outbf) {
                ushort4 u;
                u.x = f2bf(r.x); u.y = f2bf(r.y); u.z = f2bf(r.z); u.w = f2bf(r.w);
                *reinterpret_cast<ushort4*>(outbf + (size_t)node * DD + tc) = u;
            }
        }
    }
}

static inline size_t rup(size_t b) { return (b + 255) & ~(size_t)255; }

extern "C" void kernel_launch(void* const* d_in, const int* in_sizes, int n_in,
                              void* d_out, int out_size, void* d_ws, size_t ws_size,
                              hipStream_t stream) {
    const float* x   = (const float*)d_in[0];
    const int*   ei  = (const int*)d_in[1];
    const float* Wl1 = (const float*)d_in[2];
    const float* Wr1 = (const float*)d_in[3];
    const float* b1  = (const float*)d_in[4];
    const float* Wl2 = (const float*)d_in[5];
    const float* Wr2 = (const float*)d_in[6];
    const float* b2  = (const float*)d_in[7];
    float* out = (float*)d_out;

    const int* src = ei;        // edge_index[0]
    const int* dst = ei + EE;   // edge_index[1]

    // workspace layout (256B-aligned regions), ~13 MB
    char* p = (char*)d_ws;
    int* partial          = (int*)p;            p += rup((size_t)PA_BLOCKS * NBINS * 4);
    int* binCount         = (int*)p;            p += rup((size_t)NBINS * 4);
    int* binBase          = (int*)p;            p += rup((size_t)(NBINS + 1) * 4);
    int* binCursor        = (int*)p;            p += rup((size_t)NBINS * 4);
    unsigned* ebuf        = (unsigned*)p;       p += rup((size_t)EE * 4);
    unsigned short* esrc  = (unsigned short*)p; p += rup((size_t)EE * 2);
    int* offs             = (int*)p;            p += rup((size_t)(NN + 1) * 4);
    unsigned short* xbf   = (unsigned short*)p; p += rup((size_t)NN * DD * 2);
    unsigned short* hbf   = (unsigned short*)p; p += rup((size_t)NN * DD * 2);
    unsigned short* aggbf = (unsigned short*)p; p += rup((size_t)NN * DD * 2);

    // two-level CSR build (no memset anywhere) + bf16 mirror of x
    binhist_kernel<<<PA_BLOCKS, 256, 0, stream>>>(dst, partial);
    binsum_kernel<<<(NBINS + 255) / 256, 256, 0, stream>>>(partial, binCount);
    binscan_kernel<<<1, 1024, 0, stream>>>(binCount, binBase, binCursor);
    binscatter_kernel<<<PA_BLOCKS, 256, 0, stream>>>(src, dst, binCursor, ebuf);
    binsort_kernel<<<NBINS, 256, 0, stream>>>(ebuf, binBase, esrc, offs);
    cvt_kernel<<<(NN * DD / 4 + 255) / 256, 256, 0, stream>>>(x, xbf);

    // layer 1: bf16 gather -> bf16-operand GEMM, writes only hbf
    gather_kernel<<<NLB, 256, 0, stream>>>(xbf, esrc, offs, aggbf);
    layer_kernel<<<NLB, 256, 0, stream>>>(aggbf, xbf, Wl1, Wr1, b1,
                                          nullptr, hbf, 1);

    // layer 2: writes fp32 out
    gather_kernel<<<NLB, 256, 0, stream>>>(hbf, esrc, offs, aggbf);
    layer_kernel<<<NLB, 256, 0, stream>>>(aggbf, hbf, Wl2, Wr2, b2,
                                          out, nullptr, 0);
}

// Round 13
// 115.756 us; speedup vs baseline: 6.9931x; 1.0107x over previous
//
#include <hip/hip_runtime.h>
#include <hip/hip_bf16.h>

#define NN 50000
#define EE 800000
#define DD 64
#define NBINS 782                  // ceil(NN / 64)
#define PA_BLOCKS 256
#define PA_CHUNK (EE / PA_BLOCKS)  // 3125
#define NLB 1563                   // ceil(NN / 32)
#define SEGMAX 1536                // max edges per 32-node segment (45 sigma)

__device__ inline unsigned short f2bf(float f) {          // RNE float->bf16
    unsigned u = __float_as_uint(f);
    return (unsigned short)((u + 0x7FFF + ((u >> 16) & 1)) >> 16);
}
__device__ inline float bflo(unsigned u) { return __uint_as_float(u << 16); }
__device__ inline float bfhi(unsigned u) { return __uint_as_float(u & 0xFFFF0000u); }
__device__ inline unsigned bfpack(float a, float b) {     // [lo=a, hi=b]
    return (unsigned)f2bf(a) | ((unsigned)f2bf(b) << 16);
}

// ------- fp32 -> bf16 mirrors: x (blocks 0..3124) + 4 W matrices (16 blk) --
__global__ void cvt_all_kernel(const float* __restrict__ x,
                               const float* __restrict__ Wl1,
                               const float* __restrict__ Wr1,
                               const float* __restrict__ Wl2,
                               const float* __restrict__ Wr2,
                               unsigned short* __restrict__ xbf,
                               unsigned short* __restrict__ wbf) {
    const int tid = threadIdx.x;
    if (blockIdx.x < 3125) {
        int i = blockIdx.x * 256 + tid;           // float4 chunk of x
        if (i < NN * DD / 4) {
            float4 v = reinterpret_cast<const float4*>(x)[i];
            ushort4 u;
            u.x = f2bf(v.x); u.y = f2bf(v.y); u.z = f2bf(v.z); u.w = f2bf(v.w);
            reinterpret_cast<ushort4*>(xbf)[i] = u;
        }
    } else {
        int j = (blockIdx.x - 3125) * 256 + tid;  // 0..4095 float4 chunks
        int m = j >> 10, c = j & 1023;
        const float* sp = (m == 0) ? Wl1 : (m == 1) ? Wr1 : (m == 2) ? Wl2 : Wr2;
        float4 v = reinterpret_cast<const float4*>(sp)[c];
        ushort4 u;
        u.x = f2bf(v.x); u.y = f2bf(v.y); u.z = f2bf(v.z); u.w = f2bf(v.w);
        reinterpret_cast<ushort4*>(wbf)[j] = u;
    }
}

// ---------------- per-block bin histogram -> partial[block][bin] -----------
__global__ void binhist_kernel(const int* __restrict__ dst, int* __restrict__ partial) {
    __shared__ int hist[NBINS];
    const int tid = threadIdx.x;
    for (int i = tid; i < NBINS; i += 256) hist[i] = 0;
    __syncthreads();
    const int e0 = blockIdx.x * PA_CHUNK;
    for (int e = e0 + tid; e < e0 + PA_CHUNK; e += 256)
        atomicAdd(&hist[dst[e] >> 6], 1);
    __syncthreads();
    int* row = partial + (size_t)blockIdx.x * NBINS;
    for (int i = tid; i < NBINS; i += 256) row[i] = hist[i];
}

// ------- column-sum partials + exclusive scan (one block, fused) -----------
__global__ void binscan_kernel(const int* __restrict__ partial,
                               int* __restrict__ binBase, int* __restrict__ binCursor) {
    __shared__ int s[1024];
    const int tid = threadIdx.x;
    int v = 0;
    if (tid < NBINS) {
        #pragma unroll 8
        for (int b = 0; b < PA_BLOCKS; ++b)
            v += partial[(size_t)b * NBINS + tid];
    }
    s[tid] = v;
    __syncthreads();
    #pragma unroll
    for (int o = 1; o < 1024; o <<= 1) {
        int t = (tid >= o) ? s[tid - o] : 0;
        __syncthreads();
        s[tid] += t;
        __syncthreads();
    }
    if (tid < NBINS) {
        int b = s[tid] - v;        // exclusive
        binBase[tid] = b;
        binCursor[tid] = b;
    }
    if (tid == 0) binBase[NBINS] = EE;
}

// ---------------- partition edges into bin segments ------------------------
__global__ void binscatter_kernel(const int* __restrict__ src, const int* __restrict__ dst,
                                  int* __restrict__ binCursor, unsigned* __restrict__ ebuf) {
    __shared__ int hist[NBINS];
    __shared__ int base[NBINS];
    const int tid = threadIdx.x;
    for (int i = tid; i < NBINS; i += 256) hist[i] = 0;
    __syncthreads();
    const int e0 = blockIdx.x * PA_CHUNK;
    for (int e = e0 + tid; e < e0 + PA_CHUNK; e += 256)
        atomicAdd(&hist[dst[e] >> 6], 1);
    __syncthreads();
    for (int i = tid; i < NBINS; i += 256) {
        int c = hist[i];
        base[i] = c ? atomicAdd(&binCursor[i], c) : 0;
        hist[i] = 0;               // reuse as local cursor
    }
    __syncthreads();
    for (int e = e0 + tid; e < e0 + PA_CHUNK; e += 256) {
        int d = dst[e];
        int b = d >> 6;
        int off = atomicAdd(&hist[b], 1);
        ebuf[base[b] + off] = ((unsigned)(d & 63) << 16) | (unsigned)src[e];
    }
}

// ---------------- node-sort within each bin -> esrc (ushort) + offs --------
__global__ void binsort_kernel(const unsigned* __restrict__ ebuf,
                               const int* __restrict__ binBase,
                               unsigned short* __restrict__ esrc,
                               int* __restrict__ offs) {
    __shared__ int hist[64];
    __shared__ int cur[64];
    const int tid = threadIdx.x;
    const int b = blockIdx.x;
    const int e0 = binBase[b], e1 = binBase[b + 1];
    if (tid < 64) hist[tid] = 0;
    __syncthreads();
    for (int e = e0 + tid; e < e1; e += 256)
        atomicAdd(&hist[(ebuf[e] >> 16) & 63], 1);
    __syncthreads();
    if (tid == 0) {
        int run = e0;
        #pragma unroll
        for (int i = 0; i < 64; ++i) { int c = hist[i]; cur[i] = run; run += c; }
    }
    __syncthreads();
    if (tid < 64) {
        int node = b * 64 + tid;
        if (node <= NN) offs[node] = cur[tid];   // node==NN lands exactly at EE
    }
    __syncthreads();
    for (int e = e0 + tid; e < e1; e += 256) {
        unsigned p = ebuf[e];
        int n = (p >> 16) & 63;
        int pos = atomicAdd(&cur[n], 1);
        esrc[pos] = (unsigned short)(p & 0xFFFFu);
    }
}

// ---------------- gather-aggregate (bf16 in, bf16 out) ---------------------
// Block = 32 nodes. Edge indices for the whole contiguous segment staged
// into LDS (coalesced), removing the global esrc load from the address
// dependence chain; row loads 8-deep unrolled (8 uint4 in flight/lane).
__global__ void gather_kernel(const unsigned short* __restrict__ feat,
                              const unsigned short* __restrict__ esrc,
                              const int* __restrict__ offs,
                              unsigned short* __restrict__ aggbf) {
    __shared__ unsigned short eidx[SEGMAX];
    __shared__ int soff[33];
    const int tid = threadIdx.x;
    const int base = blockIdx.x * 32;
    if (tid <= 32) {
        int node = base + tid;
        soff[tid] = offs[node > NN ? NN : node];
    }
    __syncthreads();
    const int eseg = soff[0], eend = soff[32];
    for (int i = eseg + tid; i < eend; i += 256) eidx[i - eseg] = esrc[i];
    __syncthreads();

    int n = base + (tid >> 3);
    if (n >= NN) return;
    const int q = (tid & 7) << 3;         // bf16 elem offset 0,8,...,56
    int le0 = soff[tid >> 3] - eseg;
    int le1 = soff[(tid >> 3) + 1] - eseg;
    float a0 = 0.f, a1 = 0.f, a2 = 0.f, a3 = 0.f;
    float a4 = 0.f, a5 = 0.f, a6 = 0.f, a7 = 0.f;
    int e = le0;
    for (; e + 7 < le1; e += 8) {
        uint4 u0 = *reinterpret_cast<const uint4*>(feat + (size_t)eidx[e + 0] * DD + q);
        uint4 u1 = *reinterpret_cast<const uint4*>(feat + (size_t)eidx[e + 1] * DD + q);
        uint4 u2 = *reinterpret_cast<const uint4*>(feat + (size_t)eidx[e + 2] * DD + q);
        uint4 u3 = *reinterpret_cast<const uint4*>(feat + (size_t)eidx[e + 3] * DD + q);
        uint4 u4 = *reinterpret_cast<const uint4*>(feat + (size_t)eidx[e + 4] * DD + q);
        uint4 u5 = *reinterpret_cast<const uint4*>(feat + (size_t)eidx[e + 5] * DD + q);
        uint4 u6 = *reinterpret_cast<const uint4*>(feat + (size_t)eidx[e + 6] * DD + q);
        uint4 u7 = *reinterpret_cast<const uint4*>(feat + (size_t)eidx[e + 7] * DD + q);
        a0 += ((bflo(u0.x) + bflo(u1.x)) + (bflo(u2.x) + bflo(u3.x)))
            + ((bflo(u4.x) + bflo(u5.x)) + (bflo(u6.x) + bflo(u7.x)));
        a1 += ((bfhi(u0.x) + bfhi(u1.x)) + (bfhi(u2.x) + bfhi(u3.x)))
            + ((bfhi(u4.x) + bfhi(u5.x)) + (bfhi(u6.x) + bfhi(u7.x)));
        a2 += ((bflo(u0.y) + bflo(u1.y)) + (bflo(u2.y) + bflo(u3.y)))
            + ((bflo(u4.y) + bflo(u5.y)) + (bflo(u6.y) + bflo(u7.y)));
        a3 += ((bfhi(u0.y) + bfhi(u1.y)) + (bfhi(u2.y) + bfhi(u3.y)))
            + ((bfhi(u4.y) + bfhi(u5.y)) + (bfhi(u6.y) + bfhi(u7.y)));
        a4 += ((bflo(u0.z) + bflo(u1.z)) + (bflo(u2.z) + bflo(u3.z)))
            + ((bflo(u4.z) + bflo(u5.z)) + (bflo(u6.z) + bflo(u7.z)));
        a5 += ((bfhi(u0.z) + bfhi(u1.z)) + (bfhi(u2.z) + bfhi(u3.z)))
            + ((bfhi(u4.z) + bfhi(u5.z)) + (bfhi(u6.z) + bfhi(u7.z)));
        a6 += ((bflo(u0.w) + bflo(u1.w)) + (bflo(u2.w) + bflo(u3.w)))
            + ((bflo(u4.w) + bflo(u5.w)) + (bflo(u6.w) + bflo(u7.w)));
        a7 += ((bfhi(u0.w) + bfhi(u1.w)) + (bfhi(u2.w) + bfhi(u3.w)))
            + ((bfhi(u4.w) + bfhi(u5.w)) + (bfhi(u6.w) + bfhi(u7.w)));
    }
    for (; e + 1 < le1; e += 2) {
        uint4 u0 = *reinterpret_cast<const uint4*>(feat + (size_t)eidx[e + 0] * DD + q);
        uint4 u1 = *reinterpret_cast<const uint4*>(feat + (size_t)eidx[e + 1] * DD + q);
        a0 += bflo(u0.x) + bflo(u1.x); a1 += bfhi(u0.x) + bfhi(u1.x);
        a2 += bflo(u0.y) + bflo(u1.y); a3 += bfhi(u0.y) + bfhi(u1.y);
        a4 += bflo(u0.z) + bflo(u1.z); a5 += bfhi(u0.z) + bfhi(u1.z);
        a6 += bflo(u0.w) + bflo(u1.w); a7 += bfhi(u0.w) + bfhi(u1.w);
    }
    if (e < le1) {
        uint4 u0 = *reinterpret_cast<const uint4*>(feat + (size_t)eidx[e] * DD + q);
        a0 += bflo(u0.x); a1 += bfhi(u0.x);
        a2 += bflo(u0.y); a3 += bfhi(u0.y);
        a4 += bflo(u0.z); a5 += bfhi(u0.z);
        a6 += bflo(u0.w); a7 += bfhi(u0.w);
    }
    float iv = (le1 > le0) ? (1.0f / (float)(le1 - le0)) : 0.0f;
    uint4 r;
    r.x = bfpack(a0 * iv, a1 * iv);
    r.y = bfpack(a2 * iv, a3 * iv);
    r.z = bfpack(a4 * iv, a5 * iv);
    r.w = bfpack(a6 * iv, a7 * iv);
    *reinterpret_cast<uint4*>(aggbf + (size_t)n * DD + q) = r;
}

// ---------------- SAGE layer GEMM, split-K two-pass, 32-node tiles ---------
// pass 0: A = bf16 agg tile, W = bf16 Wl ; pass 1: A = bf16 self, W = bf16 Wr.
// W staged from bf16 (half the VMEM), expanded to fp32 in LDS. 24KB LDS.
__launch_bounds__(256, 6)
__global__ void layer_kernel(const unsigned short* __restrict__ aggbf,
                             const unsigned short* __restrict__ selfbf,
                             const unsigned short* __restrict__ Wbf,   // [2][64*64]
                             const float* __restrict__ bias,
                             float* __restrict__ outp,
                             unsigned short* __restrict__ outbf,
                             int relu) {
    __shared__ float A[32 * 64];    // [n][k ^ ((n&15)<<2)]
    __shared__ float W[64 * 64];    // [k][j]
    const int tid = threadIdx.x;
    const int base = blockIdx.x * 32;
    const int tc = (tid & 15) * 4;  // col base
    const int tr = (tid >> 4) * 2;  // node base (2 nodes/thread)

    float acc[2][4];
    float4 bv = *reinterpret_cast<const float4*>(bias + tc);
    #pragma unroll
    for (int i = 0; i < 2; ++i) {
        acc[i][0] = bv.x; acc[i][1] = bv.y; acc[i][2] = bv.z; acc[i][3] = bv.w;
    }

    for (int pass = 0; pass < 2; ++pass) {
        if (pass) __syncthreads();          // reads of previous tiles done
        const unsigned short* Wsrc = Wbf + pass * 4096;
        const unsigned short* Asrc = pass ? selfbf : aggbf;

        // stage W: 4096 bf16 = 512 uint4; expand to fp32 LDS
        #pragma unroll
        for (int i = 0; i < 2; ++i) {
            int idx = i * 256 + tid;        // uint4 index 0..511 (= 8 elems)
            uint4 u = reinterpret_cast<const uint4*>(Wsrc)[idx];
            float4 f0 = make_float4(bflo(u.x), bfhi(u.x), bflo(u.y), bfhi(u.y));
            float4 f1 = make_float4(bflo(u.z), bfhi(u.z), bflo(u.w), bfhi(u.w));
            *reinterpret_cast<float4*>(&W[idx * 8]) = f0;
            *reinterpret_cast<float4*>(&W[idx * 8 + 4]) = f1;
        }
        // stage A tile: 32 nodes x 64 bf16; each thread one uint4 (8 bf16)
        {
            int n  = tid >> 3;              // 0..31
            int c8 = (tid & 7) << 3;        // 0,8,...,56
            int node = base + n;
            uint4 u = make_uint4(0u, 0u, 0u, 0u);
            if (node < NN)
                u = *reinterpret_cast<const uint4*>(Asrc + (size_t)node * DD + c8);
            float4 f0 = make_float4(bflo(u.x), bfhi(u.x), bflo(u.y), bfhi(u.y));
            float4 f1 = make_float4(bflo(u.z), bfhi(u.z), bflo(u.w), bfhi(u.w));
            int sw = (n & 15) << 2;
            *reinterpret_cast<float4*>(&A[n * 64 + (c8 ^ sw)]) = f0;
            *reinterpret_cast<float4*>(&A[n * 64 + ((c8 + 4) ^ sw)]) = f1;
        }
        __syncthreads();

        #pragma unroll 4
        for (int k = 0; k < 64; k += 4) {
            float av[2][4];
            #pragma unroll
            for (int i = 0; i < 2; ++i) {
                int row = tr + i;
                float4 a = *reinterpret_cast<const float4*>(
                    &A[row * 64 + (k ^ ((row & 15) << 2))]);
                av[i][0] = a.x; av[i][1] = a.y; av[i][2] = a.z; av[i][3] = a.w;
            }
            #pragma unroll
            for (int kk = 0; kk < 4; ++kk) {
                float4 w = *reinterpret_cast<const float4*>(&W[(k + kk) * 64 + tc]);
                #pragma unroll
                for (int i = 0; i < 2; ++i) {
                    acc[i][0] += av[i][kk] * w.x;
                    acc[i][1] += av[i][kk] * w.y;
                    acc[i][2] += av[i][kk] * w.z;
                    acc[i][3] += av[i][kk] * w.w;
                }
            }
        }
    }

    #pragma unroll
    for (int i = 0; i < 2; ++i) {
        int node = base + tr + i;
        if (node < NN) {
            float4 r = make_float4(acc[i][0], acc[i][1], acc[i][2], acc[i][3]);
            if (relu) {
                r.x = fmaxf(r.x, 0.f); r.y = fmaxf(r.y, 0.f);
                r.z = fmaxf(r.z, 0.f); r.w = fmaxf(r.w, 0.f);
            }
            if (outp)
                *reinterpret_cast<float4*>(outp + (size_t)node * DD + tc) = r;
            if (outbf) {
                ushort4 u;
                u.x = f2bf(r.x); u.y = f2bf(r.y); u.z = f2bf(r.z); u.w = f2bf(r.w);
                *reinterpret_cast<ushort4*>(outbf + (size_t)node * DD + tc) = u;
            }
        }
    }
}

static inline size_t rup(size_t b) { return (b + 255) & ~(size_t)255; }

extern "C" void kernel_launch(void* const* d_in, const int* in_sizes, int n_in,
                              void* d_out, int out_size, void* d_ws, size_t ws_size,
                              hipStream_t stream) {
    const float* x   = (const float*)d_in[0];
    const int*   ei  = (const int*)d_in[1];
    const float* Wl1 = (const float*)d_in[2];
    const float* Wr1 = (const float*)d_in[3];
    const float* b1  = (const float*)d_in[4];
    const float* Wl2 = (const float*)d_in[5];
    const float* Wr2 = (const float*)d_in[6];
    const float* b2  = (const float*)d_in[7];
    float* out = (float*)d_out;

    const int* src = ei;        // edge_index[0]
    const int* dst = ei + EE;   // edge_index[1]

    // workspace layout (256B-aligned regions), ~25 MB
    char* p = (char*)d_ws;
    int* partial          = (int*)p;            p += rup((size_t)PA_BLOCKS * NBINS * 4);
    int* binBase          = (int*)p;            p += rup((size_t)(NBINS + 1) * 4);
    int* binCursor        = (int*)p;            p += rup((size_t)NBINS * 4);
    unsigned* ebuf        = (unsigned*)p;       p += rup((size_t)EE * 4);
    unsigned short* esrc  = (unsigned short*)p; p += rup((size_t)EE * 2);
    int* offs             = (int*)p;            p += rup((size_t)(NN + 1) * 4);
    unsigned short* xbf   = (unsigned short*)p; p += rup((size_t)NN * DD * 2);
    unsigned short* hbf   = (unsigned short*)p; p += rup((size_t)NN * DD * 2);
    unsigned short* aggbf = (unsigned short*)p; p += rup((size_t)NN * DD * 2);
    unsigned short* wbf   = (unsigned short*)p; p += rup((size_t)4 * 64 * 64 * 2);

    // CSR build + bf16 mirrors (no memset anywhere)
    binhist_kernel<<<PA_BLOCKS, 256, 0, stream>>>(dst, partial);
    binscan_kernel<<<1, 1024, 0, stream>>>(partial, binBase, binCursor);
    binscatter_kernel<<<PA_BLOCKS, 256, 0, stream>>>(src, dst, binCursor, ebuf);
    binsort_kernel<<<NBINS, 256, 0, stream>>>(ebuf, binBase, esrc, offs);
    cvt_all_kernel<<<3141, 256, 0, stream>>>(x, Wl1, Wr1, Wl2, Wr2, xbf, wbf);

    // layer 1: bf16 gather -> bf16-operand GEMM, writes only hbf
    gather_kernel<<<NLB, 256, 0, stream>>>(xbf, esrc, offs, aggbf);
    layer_kernel<<<NLB, 256, 0, stream>>>(aggbf, xbf, wbf, b1, nullptr, hbf, 1);

    // layer 2: writes fp32 out
    gather_kernel<<<NLB, 256, 0, stream>>>(hbf, esrc, offs, aggbf);
    layer_kernel<<<NLB, 256, 0, stream>>>(aggbf, hbf, wbf + 8192, b2, out, nullptr, 0);
}